// Round 3
// baseline (345.116 us; speedup 1.0000x reference)
//
#include <hip/hip_runtime.h>

// ---------------------------------------------------------------------------
// DualAttention on MI355X.  B=8 L=8 C=64 W=32 (WH=1024, LWH=8192) NH=128 FS=5
// R3: latency-hiding + fusion.
//  - 5 launches: K1 = prep ∪ chan_S(raw-f32, on-the-fly hi/lo, k-split 8)
//                K2 = spat_attn (kv-split 4 -> 8 waves/SIMD) ∪ chan_soft
//                K3 = spat_fin ∪ chan_B;  K4 = conv5;  K5 = finalk
//  - KCH/KCL buffers deleted (16MB less traffic).
// ---------------------------------------------------------------------------

#define LOG2E 1.44269504088896340736f

typedef __attribute__((ext_vector_type(8))) short short8;   // bf16 x8 frag
typedef __attribute__((ext_vector_type(4))) float f4;       // fp32 x4 frag

#define MFMA16(a, b, c) __builtin_amdgcn_mfma_f32_16x16x32_bf16(a, b, c, 0, 0, 0)

__device__ __forceinline__ unsigned short f2bf(float f) {   // RNE float->bf16
  union { float f; unsigned u; } v; v.f = f;
  unsigned r = v.u + 0x7FFFu + ((v.u >> 16) & 1u);
  return (unsigned short)(r >> 16);
}
__device__ __forceinline__ unsigned short f2bf_rz(float f) { // truncate (P only)
  union { float f; unsigned u; } v; v.f = f;
  return (unsigned short)(v.u >> 16);
}
__device__ __forceinline__ float bf2f(unsigned short h) {
  union { unsigned u; float f; } v; v.u = ((unsigned)h) << 16;
  return v.f;
}
__device__ __forceinline__ float exp2fast(float x) {
#if __has_builtin(__builtin_amdgcn_exp2f)
  return __builtin_amdgcn_exp2f(x);
#else
  return exp2f(x);
#endif
}

// ---------------- workspace layout (bytes), total 48,283,904 (~46MB) -------
#define O_STATS 0ul                      // [2][8][2] f32 (memset 0)
#define O_W1T   256ul                    // [2][25][64][64] bf16
#define O_W2B   409856ul                 // [2][128][64] bf16
#define O_QT    442624ul                 // [8][1024][64] bf16  q^T
#define O_KSP   1491200ul                // [8][8192][64] bf16  spatial K
#define O_VT    9879808ul                // [8][64][8192] bf16  spatial V^T
#define O_VCT   18268416ul               // [8][1024][512] bf16 channel V^T
#define O_NUM   26657024ul               // [8][64][4][16][64] f32 spat num part
#define O_DEN   35045632ul               // [8][64][4][16] f32     spat den part
#define O_SP    35176704ul               // [8][8][64][512] f32 chan S partials
#define O_PCH   43565312ul               // [8][64][512] bf16   chan P
#define O_XS    44089600ul               // [8][1024][64] bf16 stem in (spatial)
#define O_XC    45138176ul               // [8][1024][64] bf16 stem in (channel)
#define O_YT    46186752ul               // [2][8][1024][64] bf16 conv1 out

// ============================================================================
// K1: prep (tile transposes + weights) ∪ chan_S partials
//   blocks 0..1023    keys 64x64 tiles  -> KSP (transposed)
//   blocks 1024..2047 values tiles      -> VT (identity), VCT (transposed)
//   blocks 2048..2175 q tiles           -> QT (transposed)
//   blocks 2176..3039 weights           -> W1T, W2B
//   blocks 3040..3551 chan_S: S_part[64 x 64cols] over 128 channels (k-split 8)
// ============================================================================
__global__ __launch_bounds__(256) void k1_prep_chanS(
    const float* __restrict__ q, const float* __restrict__ keys,
    const float* __restrict__ values,
    const float* __restrict__ sw1, const float* __restrict__ sw2,
    const float* __restrict__ cw1, const float* __restrict__ cw2,
    char* __restrict__ ws)
{
  __shared__ float T[64][65];
  const int job = blockIdx.x, t = threadIdx.x;

  if (job < 2176) {                      // ---- tile transposes ----
    unsigned short* VTp = (unsigned short*)(ws + O_VT);
    unsigned short* KSP = (unsigned short*)(ws + O_KSP);
    unsigned short* VCT = (unsigned short*)(ws + O_VCT);
    unsigned short* QT  = (unsigned short*)(ws + O_QT);
    int kind, mat;
    if (job < 1024)      { kind = 0; mat = job >> 4; }
    else if (job < 2048) { kind = 1; mat = (job - 1024) >> 4; }
    else                 { kind = 2; mat = (job - 2048) >> 4; }
    const int pt = job & 15, p0 = pt * 64;
    const float* src = (kind == 0 ? keys : kind == 1 ? values : q) + (size_t)mat * 65536;

    const int r0 = t >> 4, c4 = (t & 15) * 4;
#pragma unroll
    for (int pass = 0; pass < 4; ++pass) {
      const int r = pass * 16 + r0;
      float4 v = *(const float4*)(src + (size_t)r * 1024 + p0 + c4);
      float vv[4] = {v.x, v.y, v.z, v.w};
      T[r][c4] = vv[0]; T[r][c4 + 1] = vv[1]; T[r][c4 + 2] = vv[2]; T[r][c4 + 3] = vv[3];
      if (kind == 1) {                   // spatial V^T[b][c][l*1024+p]
        int b = mat >> 3, l = mat & 7;
        size_t gi = ((size_t)b * 64 + r) * 8192 + l * 1024 + p0 + c4;
        ushort4 o; unsigned short* op = (unsigned short*)&o;
#pragma unroll
        for (int j = 0; j < 4; ++j) op[j] = f2bf(vv[j]);
        *(ushort4*)(VTp + gi) = o;
      }
    }
    __syncthreads();
#pragma unroll
    for (int pass = 0; pass < 2; ++pass) {
      const int p = pass * 32 + (t >> 3), cs = (t & 7) * 8;
      short8 o;
#pragma unroll
      for (int j = 0; j < 8; ++j) o[j] = (short)f2bf(T[cs + j][p]);
      if (kind == 0) {                   // Ksp[b][l*1024+p][c]
        int b = mat >> 3, l = mat & 7;
        *(short8*)(KSP + ((size_t)b * 8192 + l * 1024 + p0 + p) * 64 + cs) = o;
      } else if (kind == 1) {            // Vct[b][p][l*64+c]
        int b = mat >> 3, l = mat & 7;
        *(short8*)(VCT + ((size_t)b * 1024 + p0 + p) * 512 + l * 64 + cs) = o;
      } else {                           // Qt[b][p][c]
        *(short8*)(QT + ((size_t)mat * 1024 + p0 + p) * 64 + cs) = o;
      }
    }
    return;
  }

  if (job < 3040) {                      // ---- weights ----
    unsigned i = (job - 2176) * 256u + t;
    if (i < 204800u) {                   // W1t[s][off][co][ci] <- w1[co][ci][off]
      unsigned ci = i & 63u, co = (i >> 6) & 63u, tt = i >> 12;
      unsigned off = tt % 25u, st = tt / 25u;
      const float* w = st ? cw1 : sw1;
      ((unsigned short*)(ws + O_W1T))[i] = f2bf(w[(co * 64u + ci) * 25u + off]);
      return;
    }
    i -= 204800u;
    if (i < 16384u) {                    // W2b[s][nh][c]
      unsigned c = i & 63u, nh = (i >> 6) & 127u, st = i >> 13;
      const float* w = st ? cw2 : sw2;
      ((unsigned short*)(ws + O_W2B))[i] = f2bf(w[nh * 64u + c]);
    }
    return;
  }

  // ---- chan_S: 512 blocks = (b:8) x (colT:8 of 64 cols) x (kt:8 of 128 ch)
  {
    float* Sp = (float*)(ws + O_SP);
    const int bid = job - 3040;
    const int b = bid >> 6, colT = (bid >> 3) & 7, kt = bid & 7;
    const int w = t >> 6, lane = t & 63;
    const int low4 = lane & 15, quad = lane >> 4;
    const int col0 = colT * 64 + w * 16;

    f4 acc[4];
#pragma unroll
    for (int m = 0; m < 4; ++m) acc[m] = (f4){0.f, 0.f, 0.f, 0.f};

#pragma unroll
    for (int kst = 0; kst < 4; ++kst) {
      const int k = kt * 128 + kst * 32 + quad * 8;
      // B frag: keys row (b*512+col), hi/lo split on the fly
      const float* kp = keys + ((size_t)(b * 512 + col0 + low4)) * 1024 + k;
      float4 u0 = *(const float4*)kp;
      float4 u1 = *(const float4*)(kp + 4);
      float kv[8] = {u0.x, u0.y, u0.z, u0.w, u1.x, u1.y, u1.z, u1.w};
      short8 bh, bl;
#pragma unroll
      for (int j = 0; j < 8; ++j) {
        unsigned short hi = f2bf(kv[j]);
        bh[j] = (short)hi;
        bl[j] = (short)f2bf(kv[j] - bf2f(hi));
      }
#pragma unroll
      for (int m = 0; m < 4; ++m) {
        const float* qp = q + ((size_t)(b * 64 + m * 16 + low4)) * 1024 + k;
        float4 w0 = *(const float4*)qp;
        float4 w1 = *(const float4*)(qp + 4);
        float qv[8] = {w0.x, w0.y, w0.z, w0.w, w1.x, w1.y, w1.z, w1.w};
        short8 ah, al;
#pragma unroll
        for (int j = 0; j < 8; ++j) {
          float sv = qv[j] * LOG2E;
          unsigned short hi = f2bf(sv);
          ah[j] = (short)hi;
          al[j] = (short)f2bf(sv - bf2f(hi));
        }
        acc[m] = MFMA16(ah, bh, acc[m]);
        acc[m] = MFMA16(al, bh, acc[m]);
        acc[m] = MFMA16(ah, bl, acc[m]);
      }
    }
#pragma unroll
    for (int m = 0; m < 4; ++m)
#pragma unroll
      for (int r = 0; r < 4; ++r)
        Sp[(((size_t)kt * 8 + b) * 64 + m * 16 + quad * 4 + r) * 512 + col0 + low4] = acc[m][r];
  }
}

// ============================================================================
// K2: spat_attn (2048 blocks, kv-split 4) ∪ chan_soft (32 blocks)
// ============================================================================
__global__ __launch_bounds__(256, 8) void k2_spat_soft(char* __restrict__ ws)
{
  __shared__ __align__(16) float Osum[4][16][64];          // 16KB
  __shared__ float Dsum[4][16];

  if (blockIdx.x < 2048) {               // ---- spatial flash attention ----
    const unsigned short* QT = (const unsigned short*)(ws + O_QT);
    const unsigned short* Ks = (const unsigned short*)(ws + O_KSP);
    const unsigned short* Vt = (const unsigned short*)(ws + O_VT);
    float* NUM = (float*)(ws + O_NUM);
    float* DEN = (float*)(ws + O_DEN);

    const int b = blockIdx.x >> 8;
    const int qt = (blockIdx.x >> 2) & 63;
    const int s = blockIdx.x & 3;
    const int w = threadIdx.x >> 6, lane = threadIdx.x & 63;
    const int low4 = lane & 15, quad = lane >> 4;

    unsigned short (*Plds)[16][72] =
        reinterpret_cast<unsigned short(*)[16][72]>(&Osum[0][0][0]);

    const unsigned short* Qb = QT + ((size_t)(b * 1024 + qt * 16)) * 64;
    short8 qa[2];
#pragma unroll
    for (int ks = 0; ks < 2; ++ks) {
      short8 qr = *(const short8*)(Qb + low4 * 64 + ks * 32 + quad * 8);
      short8 qs;
#pragma unroll
      for (int j = 0; j < 8; ++j) qs[j] = (short)f2bf(bf2f((unsigned short)qr[j]) * LOG2E);
      qa[ks] = qs;
    }

    f4 accO[4];
    float den[4];
#pragma unroll
    for (int n = 0; n < 4; ++n) accO[n] = (f4){0.f, 0.f, 0.f, 0.f};
#pragma unroll
    for (int r = 0; r < 4; ++r) den[r] = 0.f;

    const unsigned short* Kb = Ks + (size_t)b * 8192 * 64;
    const unsigned short* Vb = Vt + (size_t)b * 64 * 8192;

    for (int it = 0; it < 8; ++it) {
      const int kv0 = s * 2048 + it * 256 + w * 64;
      f4 sS[4];
#pragma unroll
      for (int n = 0; n < 4; ++n) sS[n] = (f4){0.f, 0.f, 0.f, 0.f};
#pragma unroll
      for (int ks = 0; ks < 2; ++ks)
#pragma unroll
        for (int n = 0; n < 4; ++n) {
          short8 kb = *(const short8*)(Kb + (size_t)(kv0 + n * 16 + low4) * 64 + ks * 32 + quad * 8);
          sS[n] = MFMA16(qa[ks], kb, sS[n]);
        }
#pragma unroll
      for (int n = 0; n < 4; ++n)
#pragma unroll
        for (int r = 0; r < 4; ++r) {
          float e = exp2fast(sS[n][r]);
          den[r] += e;
          Plds[w][quad * 4 + r][n * 16 + low4] = f2bf_rz(e);
        }
#pragma unroll
      for (int ks = 0; ks < 2; ++ks) {
        short8 pa = *(const short8*)&Plds[w][low4][ks * 32 + quad * 8];
#pragma unroll
        for (int n = 0; n < 4; ++n) {
          short8 vb = *(const short8*)(Vb + (size_t)(n * 16 + low4) * 8192 + kv0 + ks * 32 + quad * 8);
          accO[n] = MFMA16(pa, vb, accO[n]);
        }
      }
    }

#pragma unroll
    for (int r = 0; r < 4; ++r)
#pragma unroll
      for (int o = 1; o < 16; o <<= 1) den[r] += __shfl_xor(den[r], o, 64);

    __syncthreads();
#pragma unroll
    for (int n = 0; n < 4; ++n)
#pragma unroll
      for (int r = 0; r < 4; ++r)
        Osum[w][quad * 4 + r][n * 16 + low4] = accO[n][r];
    if (low4 == 0) {
#pragma unroll
      for (int r = 0; r < 4; ++r) Dsum[w][quad * 4 + r] = den[r];
    }
    __syncthreads();

    const int t = threadIdx.x;
    if (t < 128) {
      const int qrow = t >> 3, c0 = (t & 7) * 8;
      float n8[8];
#pragma unroll
      for (int j = 0; j < 8; ++j)
        n8[j] = Osum[0][qrow][c0 + j] + Osum[1][qrow][c0 + j] +
                Osum[2][qrow][c0 + j] + Osum[3][qrow][c0 + j];
      size_t base = (((size_t)(b * 64 + qt) * 4 + s) * 16 + qrow) * 64 + c0;
      *(float4*)(NUM + base)     = (float4){n8[0], n8[1], n8[2], n8[3]};
      *(float4*)(NUM + base + 4) = (float4){n8[4], n8[5], n8[6], n8[7]};
      if (c0 == 0)
        DEN[((size_t)(b * 64 + qt) * 4 + s) * 16 + qrow] =
            Dsum[0][qrow] + Dsum[1][qrow] + Dsum[2][qrow] + Dsum[3][qrow];
    }
    return;
  }

  // ---- chan_soft: sum 8 partials, max-sub, exp2, normalize -> P ----
  {
    const float* Sp = (const float*)(ws + O_SP);
    unsigned short* P = (unsigned short*)(ws + O_PCH);
    const int bid = blockIdx.x - 2048;
    const int b = bid >> 2, rt = bid & 3;
    const int row = rt * 16 + (threadIdx.x >> 4), tc = threadIdx.x & 15;

    float sv[32];
    float mx = -1e30f;
#pragma unroll
    for (int jj = 0; jj < 32; ++jj) {
      const int col = jj * 16 + tc;
      size_t base = ((size_t)b * 64 + row) * 512 + col;
      float v = 0.f;
#pragma unroll
      for (int kt = 0; kt < 8; ++kt) v += Sp[base + (size_t)kt * 262144];
      sv[jj] = v;
      mx = fmaxf(mx, v);
    }
#pragma unroll
    for (int o = 1; o < 16; o <<= 1) mx = fmaxf(mx, __shfl_xor(mx, o, 64));
    float sum = 0.f;
#pragma unroll
    for (int jj = 0; jj < 32; ++jj) {
      float e = exp2fast(sv[jj] - mx);
      sv[jj] = e;
      sum += e;
    }
#pragma unroll
    for (int o = 1; o < 16; o <<= 1) sum += __shfl_xor(sum, o, 64);
    const float rs = 1.0f / sum;
#pragma unroll
    for (int jj = 0; jj < 32; ++jj)
      P[((size_t)b * 64 + row) * 512 + jj * 16 + tc] = f2bf(sv[jj] * rs);
  }
}

// ============================================================================
// K3: spat_fin (256 blocks) ∪ chan_B (128 blocks)
// ============================================================================
__global__ __launch_bounds__(256) void k3_fin_chanB(char* __restrict__ ws)
{
  const unsigned short* QT = (const unsigned short*)(ws + O_QT);

  if (blockIdx.x < 256) {                // ---- spat_fin: 4 partials ----
    const float* NUM = (const float*)(ws + O_NUM);
    const float* DEN = (const float*)(ws + O_DEN);
    unsigned short* Xs = (unsigned short*)(ws + O_XS);

    const unsigned i = blockIdx.x * 256u + threadIdx.x;   // 65536
    const int c0 = (i & 7) * 8;
    const unsigned row = i >> 3;                          // [0, 8192)
    const int b = row >> 10, p = row & 1023;
    const int qt = p >> 4, r16 = p & 15;
    size_t nb = (((size_t)(b * 64 + qt) * 4) * 16 + r16) * 64 + c0;
    size_t di = ((size_t)(b * 64 + qt) * 4) * 16 + r16;
    float n8[8] = {0, 0, 0, 0, 0, 0, 0, 0};
    float dtot = 0.f;
#pragma unroll
    for (int s = 0; s < 4; ++s) {
      float4 x0 = *(const float4*)(NUM + nb + s * 1024);
      float4 x1 = *(const float4*)(NUM + nb + s * 1024 + 4);
      n8[0] += x0.x; n8[1] += x0.y; n8[2] += x0.z; n8[3] += x0.w;
      n8[4] += x1.x; n8[5] += x1.y; n8[6] += x1.z; n8[7] += x1.w;
      dtot += DEN[di + s * 16];
    }
    float rd = 1.0f / dtot;
    size_t ob = (size_t)row * 64 + c0;
    short8 qv = *(const short8*)(QT + ob);
    short8 o8;
#pragma unroll
    for (int j = 0; j < 8; ++j)
      o8[j] = (short)f2bf(n8[j] * rd + bf2f((unsigned short)qv[j]));
    *(short8*)(Xs + ob) = o8;
    return;
  }

  // ---- chan_B: O = P @ Vc + residual ----
  {
    const unsigned short* P = (const unsigned short*)(ws + O_PCH);
    const unsigned short* Vct = (const unsigned short*)(ws + O_VCT);
    unsigned short* Xc = (unsigned short*)(ws + O_XC);

    const int bid = blockIdx.x - 256;
    const int b = bid >> 4, pt = bid & 15;
    const int w = threadIdx.x >> 6, lane = threadIdx.x & 63;
    const int low4 = lane & 15, quad = lane >> 4;
    const int p = pt * 64 + w * 16 + low4;

    f4 acc[4];
#pragma unroll
    for (int m = 0; m < 4; ++m) acc[m] = (f4){0.f, 0.f, 0.f, 0.f};

    for (int ks = 0; ks < 16; ++ks) {
      short8 vb = *(const short8*)(Vct + ((size_t)(b * 1024 + p)) * 512 + ks * 32 + quad * 8);
#pragma unroll
      for (int m = 0; m < 4; ++m) {
        short8 a = *(const short8*)(P + ((size_t)(b * 64 + m * 16 + low4)) * 512 + ks * 32 + quad * 8);
        acc[m] = MFMA16(a, vb, acc[m]);
      }
    }
#pragma unroll
    for (int m = 0; m < 4; ++m)
#pragma unroll
      for (int r = 0; r < 4; ++r) {
        const int c = m * 16 + quad * 4 + r;
        size_t o = ((size_t)(b * 1024 + p)) * 64 + c;
        Xc[o] = f2bf(acc[m][r] + bf2f(QT[o]));
      }
  }
}

// ============================================================================
// K4: conv 5x5 + bias + LN stats.  512 blocks = (s:2)x(b:8)x(pt:32 of 32px),
// 256 thr: wave = (half: off 0..12|13..24) x (wsub: 16-px).  half1 -> LDS.
// ============================================================================
__global__ __launch_bounds__(256) void k4_conv5(char* __restrict__ ws,
                                                const float* __restrict__ sb1,
                                                const float* __restrict__ cb1)
{
  const int id = blockIdx.x;
  const int s = id >> 8, b = (id >> 5) & 7, pt = id & 31;
  const int w = threadIdx.x >> 6, lane = threadIdx.x & 63;
  const int low4 = lane & 15, quad = lane >> 4;
  const int wsub = w & 1, half = w >> 1;

  const unsigned short* X = (const unsigned short*)(ws + (s ? O_XC : O_XS));
  const unsigned short* W1t = (const unsigned short*)(ws + O_W1T);
  unsigned short* Yt = (unsigned short*)(ws + O_YT);
  float* stats = (float*)(ws + O_STATS);
  const float* b1p = s ? cb1 : sb1;

  __shared__ float Hbuf[2][16][65];
  __shared__ float red[2][2];

  const int p = pt * 32 + wsub * 16 + low4;
  const int y0 = p >> 5, x0 = p & 31;

  f4 acc[4];
#pragma unroll
  for (int m = 0; m < 4; ++m) acc[m] = (f4){0.f, 0.f, 0.f, 0.f};

  const int o0 = half ? 13 : 0, o1 = half ? 25 : 13;
  for (int off = o0; off < o1; ++off) {
    const int dy = off / 5 - 2, dx = off % 5 - 2;
    const int ys = y0 + dy, xs = x0 + dx;
    const bool valid = ((unsigned)ys < 32u) & ((unsigned)xs < 32u);
    const int psrc = valid ? (p + dy * 32 + dx) : p;
    const unsigned short* xp = X + ((size_t)(b * 1024 + psrc)) * 64;
    const unsigned short* wp = W1t + ((size_t)((s * 25 + off) * 64)) * 64;
#pragma unroll
    for (int ks = 0; ks < 2; ++ks) {
      short8 bv = *(const short8*)(xp + ks * 32 + quad * 8);
      if (!valid) bv = (short8)0;
#pragma unroll
      for (int m = 0; m < 4; ++m) {
        short8 av = *(const short8*)(wp + (m * 16 + low4) * 64 + ks * 32 + quad * 8);
        acc[m] = MFMA16(av, bv, acc[m]);
      }
    }
  }

  if (half) {
#pragma unroll
    for (int m = 0; m < 4; ++m)
#pragma unroll
      for (int r = 0; r < 4; ++r)
        Hbuf[wsub][low4][m * 16 + quad * 4 + r] = acc[m][r];
  }
  __syncthreads();
  if (!half) {
    float ls = 0.f, ls2 = 0.f;
#pragma unroll
    for (int m = 0; m < 4; ++m)
#pragma unroll
      for (int r = 0; r < 4; ++r) {
        const int co = m * 16 + quad * 4 + r;
        float y = acc[m][r] + Hbuf[wsub][low4][co] + b1p[co];
        Yt[((size_t)((s * 8 + b) * 1024 + p)) * 64 + co] = f2bf(y);
        ls += y; ls2 += y * y;
      }
#pragma unroll
    for (int o = 1; o < 64; o <<= 1) {
      ls += __shfl_xor(ls, o, 64);
      ls2 += __shfl_xor(ls2, o, 64);
    }
    if (lane == 0) { red[0][wsub] = ls; red[1][wsub] = ls2; }
  }
  __syncthreads();
  if (threadIdx.x == 0) {
    atomicAdd(&stats[(s * 8 + b) * 2 + 0], red[0][0] + red[0][1]);
    atomicAdd(&stats[(s * 8 + b) * 2 + 1], red[1][0] + red[1][1]);
  }
}

// ============================================================================
// K5: LN + ReLU + 1x1 conv epilogue.  256 blocks = (s:2)x(b:8)x(pt:16).
// ============================================================================
__global__ __launch_bounds__(256) void k5_final(char* __restrict__ ws,
                                                const float* __restrict__ slnw,
                                                const float* __restrict__ slnb,
                                                const float* __restrict__ clnw,
                                                const float* __restrict__ clnb,
                                                const float* __restrict__ sb2,
                                                const float* __restrict__ cb2,
                                                float* __restrict__ out)
{
  const int id = blockIdx.x;
  const int s = id >> 7, b = (id >> 4) & 7, pt = id & 15;
  const int w = threadIdx.x >> 6, lane = threadIdx.x & 63;
  const int low4 = lane & 15, quad = lane >> 4;
  const int p2 = pt * 64 + w * 16 + low4;

  const unsigned short* Yt = (const unsigned short*)(ws + O_YT);
  const unsigned short* W2b = (const unsigned short*)(ws + O_W2B);
  const float* stats = (const float*)(ws + O_STATS);
  const float* lw = s ? clnw : slnw;
  const float* lb = s ? clnb : slnb;
  const float* b2p = s ? cb2 : sb2;

  const float inv = 1.0f / 65536.0f;
  const float mu = stats[(s * 8 + b) * 2 + 0] * inv;
  const float ms = stats[(s * 8 + b) * 2 + 1] * inv;
  const float rsig = rsqrtf(ms - mu * mu + 1e-5f);

  f4 acc[8];
#pragma unroll
  for (int m = 0; m < 8; ++m) acc[m] = (f4){0.f, 0.f, 0.f, 0.f};

#pragma unroll
  for (int ks = 0; ks < 2; ++ks) {
    size_t yo = ((size_t)((s * 8 + b) * 1024 + p2)) * 64 + ks * 32 + quad * 8;
    short8 yv = *(const short8*)(Yt + yo);
    short8 zv;
#pragma unroll
    for (int j = 0; j < 8; ++j) {
      const int c = ks * 32 + quad * 8 + j;
      float z = (bf2f((unsigned short)yv[j]) - mu) * rsig * lw[c * 1024 + p2] + lb[c * 1024 + p2];
      zv[j] = (short)f2bf(fmaxf(z, 0.f));
    }
#pragma unroll
    for (int m = 0; m < 8; ++m) {
      short8 a = *(const short8*)(W2b + ((size_t)(s * 128 + m * 16 + low4)) * 64 + ks * 32 + quad * 8);
      acc[m] = MFMA16(a, zv, acc[m]);
    }
  }
#pragma unroll
  for (int m = 0; m < 8; ++m)
#pragma unroll
    for (int r = 0; r < 4; ++r) {
      const int nh = m * 16 + quad * 4 + r;
      out[((size_t)((s * 8 + b) * 128 + nh)) * 1024 + p2] = acc[m][r] + b2p[nh];
    }
}

extern "C" void kernel_launch(void* const* d_in, const int* in_sizes, int n_in,
                              void* d_out, int out_size, void* d_ws, size_t ws_size,
                              hipStream_t stream)
{
  const float* q    = (const float*)d_in[0];
  const float* keys = (const float*)d_in[1];
  const float* vals = (const float*)d_in[2];
  const float* sw1  = (const float*)d_in[3];
  const float* sb1  = (const float*)d_in[4];
  const float* slnw = (const float*)d_in[5];
  const float* slnb = (const float*)d_in[6];
  const float* sw2  = (const float*)d_in[7];
  const float* sb2  = (const float*)d_in[8];
  const float* cw1  = (const float*)d_in[9];
  const float* cb1  = (const float*)d_in[10];
  const float* clnw = (const float*)d_in[11];
  const float* clnb = (const float*)d_in[12];
  const float* cw2  = (const float*)d_in[13];
  const float* cb2  = (const float*)d_in[14];
  char* ws = (char*)d_ws;

  hipMemsetAsync(ws + O_STATS, 0, 256, stream);
  k1_prep_chanS<<<3552, 256, 0, stream>>>(q, keys, vals, sw1, sw2, cw1, cw2, ws);
  k2_spat_soft<<<2080, 256, 0, stream>>>(ws);
  k3_fin_chanB<<<384, 256, 0, stream>>>(ws);
  k4_conv5<<<512, 256, 0, stream>>>(ws, sb1, cb1);
  k5_final<<<256, 256, 0, stream>>>(ws, slnw, slnb, clnw, clnb, sb2, cb2, (float*)d_out);
}

// Round 4
// 235.856 us; speedup vs baseline: 1.4633x; 1.4633x over previous
//
#include <hip/hip_runtime.h>

// ---------------------------------------------------------------------------
// DualAttention on MI355X.  B=8 L=8 C=64 W=32 (WH=1024, LWH=8192) NH=128 FS=5
// R4: spat_attn rewritten as LDS-tiled GEMM-style flash attention.
//  - block = 128 q-rows (4 waves x M=2 tiles), kv-split 8 -> grid 512.
//  - K/V tiles staged in LDS in A-frag chunk order (conflict-free b128).
//  - each K/V frag feeds 2 MFMAs (register reuse) -> 8x less global traffic.
//  - NUM partials in bf16.  No __launch_bounds__ min-waves (R3 spill lesson).
// ---------------------------------------------------------------------------

#define LOG2E 1.44269504088896340736f

typedef __attribute__((ext_vector_type(8))) short short8;   // bf16 x8 frag
typedef __attribute__((ext_vector_type(4))) float f4;       // fp32 x4 frag

#define MFMA16(a, b, c) __builtin_amdgcn_mfma_f32_16x16x32_bf16(a, b, c, 0, 0, 0)

__device__ __forceinline__ unsigned short f2bf(float f) {   // RNE float->bf16
  union { float f; unsigned u; } v; v.f = f;
  unsigned r = v.u + 0x7FFFu + ((v.u >> 16) & 1u);
  return (unsigned short)(r >> 16);
}
__device__ __forceinline__ unsigned short f2bf_rz(float f) { // truncate (P only)
  union { float f; unsigned u; } v; v.f = f;
  return (unsigned short)(v.u >> 16);
}
__device__ __forceinline__ float bf2f(unsigned short h) {
  union { unsigned u; float f; } v; v.u = ((unsigned)h) << 16;
  return v.f;
}
__device__ __forceinline__ float exp2fast(float x) {
#if __has_builtin(__builtin_amdgcn_exp2f)
  return __builtin_amdgcn_exp2f(x);
#else
  return exp2f(x);
#endif
}

// ---------------- workspace layout (bytes), total ~48.4MB ------------------
#define O_STATS 0ul                      // [2][8][2] f32 (memset 0)
#define O_W1T   256ul                    // [2][25][64][64] bf16
#define O_W2B   409856ul                 // [2][128][64] bf16
#define O_QT    442624ul                 // [8][1024][64] bf16  q^T
#define O_KSP   1491200ul                // [8][8192][64] bf16  spatial K
#define O_VT    9879808ul                // [8][64][8192] bf16  spatial V^T
#define O_VCT   18268416ul               // [8][1024][512] bf16 channel V^T
#define O_NUM   26657024ul               // [8][1024][8][64] bf16 spat num part
#define O_DEN   35045632ul               // [8][1024][8] f32      spat den part
#define O_SP    35307776ul               // [8][8][64][512] f32 chan S partials
#define O_PCH   43696384ul               // [8][64][512] bf16   chan P
#define O_XS    44220672ul               // [8][1024][64] bf16 stem in (spatial)
#define O_XC    45269248ul               // [8][1024][64] bf16 stem in (channel)
#define O_YT    46317824ul               // [2][8][1024][64] bf16 conv1 out

// ============================================================================
// K1: prep (tile transposes + weights) ∪ chan_S partials   (grid 3552)
// ============================================================================
__global__ __launch_bounds__(256) void k1_prep_chanS(
    const float* __restrict__ q, const float* __restrict__ keys,
    const float* __restrict__ values,
    const float* __restrict__ sw1, const float* __restrict__ sw2,
    const float* __restrict__ cw1, const float* __restrict__ cw2,
    char* __restrict__ ws)
{
  __shared__ float T[64][65];
  const int job = blockIdx.x, t = threadIdx.x;

  if (job < 2176) {                      // ---- tile transposes ----
    unsigned short* VTp = (unsigned short*)(ws + O_VT);
    unsigned short* KSP = (unsigned short*)(ws + O_KSP);
    unsigned short* VCT = (unsigned short*)(ws + O_VCT);
    unsigned short* QT  = (unsigned short*)(ws + O_QT);
    int kind, mat;
    if (job < 1024)      { kind = 0; mat = job >> 4; }
    else if (job < 2048) { kind = 1; mat = (job - 1024) >> 4; }
    else                 { kind = 2; mat = (job - 2048) >> 4; }
    const int pt = job & 15, p0 = pt * 64;
    const float* src = (kind == 0 ? keys : kind == 1 ? values : q) + (size_t)mat * 65536;

    const int r0 = t >> 4, c4 = (t & 15) * 4;
#pragma unroll
    for (int pass = 0; pass < 4; ++pass) {
      const int r = pass * 16 + r0;
      float4 v = *(const float4*)(src + (size_t)r * 1024 + p0 + c4);
      float vv[4] = {v.x, v.y, v.z, v.w};
      T[r][c4] = vv[0]; T[r][c4 + 1] = vv[1]; T[r][c4 + 2] = vv[2]; T[r][c4 + 3] = vv[3];
      if (kind == 1) {                   // spatial V^T[b][c][l*1024+p]
        int b = mat >> 3, l = mat & 7;
        size_t gi = ((size_t)b * 64 + r) * 8192 + l * 1024 + p0 + c4;
        ushort4 o; unsigned short* op = (unsigned short*)&o;
#pragma unroll
        for (int j = 0; j < 4; ++j) op[j] = f2bf(vv[j]);
        *(ushort4*)(VTp + gi) = o;
      }
    }
    __syncthreads();
#pragma unroll
    for (int pass = 0; pass < 2; ++pass) {
      const int p = pass * 32 + (t >> 3), cs = (t & 7) * 8;
      short8 o;
#pragma unroll
      for (int j = 0; j < 8; ++j) o[j] = (short)f2bf(T[cs + j][p]);
      if (kind == 0) {                   // Ksp[b][l*1024+p][c]
        int b = mat >> 3, l = mat & 7;
        *(short8*)(KSP + ((size_t)b * 8192 + l * 1024 + p0 + p) * 64 + cs) = o;
      } else if (kind == 1) {            // Vct[b][p][l*64+c]
        int b = mat >> 3, l = mat & 7;
        *(short8*)(VCT + ((size_t)b * 1024 + p0 + p) * 512 + l * 64 + cs) = o;
      } else {                           // Qt[b][p][c]
        *(short8*)(QT + ((size_t)mat * 1024 + p0 + p) * 64 + cs) = o;
      }
    }
    return;
  }

  if (job < 3040) {                      // ---- weights ----
    unsigned i = (job - 2176) * 256u + t;
    if (i < 204800u) {                   // W1t[s][off][co][ci] <- w1[co][ci][off]
      unsigned ci = i & 63u, co = (i >> 6) & 63u, tt = i >> 12;
      unsigned off = tt % 25u, st = tt / 25u;
      const float* w = st ? cw1 : sw1;
      ((unsigned short*)(ws + O_W1T))[i] = f2bf(w[(co * 64u + ci) * 25u + off]);
      return;
    }
    i -= 204800u;
    if (i < 16384u) {                    // W2b[s][nh][c]
      unsigned c = i & 63u, nh = (i >> 6) & 127u, st = i >> 13;
      const float* w = st ? cw2 : sw2;
      ((unsigned short*)(ws + O_W2B))[i] = f2bf(w[nh * 64u + c]);
    }
    return;
  }

  // ---- chan_S: 512 blocks = (b:8) x (colT:8 of 64 cols) x (kt:8 of 128 ch)
  {
    float* Sp = (float*)(ws + O_SP);
    const int bid = job - 3040;
    const int b = bid >> 6, colT = (bid >> 3) & 7, kt = bid & 7;
    const int w = t >> 6, lane = t & 63;
    const int low4 = lane & 15, quad = lane >> 4;
    const int col0 = colT * 64 + w * 16;

    f4 acc[4];
#pragma unroll
    for (int m = 0; m < 4; ++m) acc[m] = (f4){0.f, 0.f, 0.f, 0.f};

#pragma unroll
    for (int kst = 0; kst < 4; ++kst) {
      const int k = kt * 128 + kst * 32 + quad * 8;
      const float* kp = keys + ((size_t)(b * 512 + col0 + low4)) * 1024 + k;
      float4 u0 = *(const float4*)kp;
      float4 u1 = *(const float4*)(kp + 4);
      float kv[8] = {u0.x, u0.y, u0.z, u0.w, u1.x, u1.y, u1.z, u1.w};
      short8 bh, bl;
#pragma unroll
      for (int j = 0; j < 8; ++j) {
        unsigned short hi = f2bf(kv[j]);
        bh[j] = (short)hi;
        bl[j] = (short)f2bf(kv[j] - bf2f(hi));
      }
#pragma unroll
      for (int m = 0; m < 4; ++m) {
        const float* qp = q + ((size_t)(b * 64 + m * 16 + low4)) * 1024 + k;
        float4 w0 = *(const float4*)qp;
        float4 w1 = *(const float4*)(qp + 4);
        float qv[8] = {w0.x, w0.y, w0.z, w0.w, w1.x, w1.y, w1.z, w1.w};
        short8 ah, al;
#pragma unroll
        for (int j = 0; j < 8; ++j) {
          float sv = qv[j] * LOG2E;
          unsigned short hi = f2bf(sv);
          ah[j] = (short)hi;
          al[j] = (short)f2bf(sv - bf2f(hi));
        }
        acc[m] = MFMA16(ah, bh, acc[m]);
        acc[m] = MFMA16(al, bh, acc[m]);
        acc[m] = MFMA16(ah, bl, acc[m]);
      }
    }
#pragma unroll
    for (int m = 0; m < 4; ++m)
#pragma unroll
      for (int r = 0; r < 4; ++r)
        Sp[(((size_t)kt * 8 + b) * 64 + m * 16 + quad * 4 + r) * 512 + col0 + low4] = acc[m][r];
  }
}

// ============================================================================
// K2: spat_attn (512 blocks, LDS-tiled) ∪ chan_soft (32 blocks)
// spat: block = (b:8)x(qt:8 of 128 q-rows)x(s:8 kv-eighths of 1024).
//   per iter (64 kv): stage K-tile[64kv][64ch] + V-tile[64ch][64kv] into LDS
//   as A/B-frag-ordered 16B chunks (linear lane sweep, conflict-free);
//   each wave: M=2 q-tiles -> 16 QK MFMA + exp2 -> P(LDS) -> 16 PV MFMA.
// ============================================================================
__global__ __launch_bounds__(256) void k2_spat_soft(char* __restrict__ ws)
{
  __shared__ __align__(16) unsigned short Kt[4096];        // 8KB
  __shared__ __align__(16) unsigned short Vt[4096];        // 8KB
  __shared__ __align__(16) unsigned short Plds[4][32][72]; // 18KB

  if (blockIdx.x < 512) {
    const unsigned short* QT = (const unsigned short*)(ws + O_QT);
    const unsigned short* KSP = (const unsigned short*)(ws + O_KSP);
    const unsigned short* VTg = (const unsigned short*)(ws + O_VT);
    unsigned short* NUM = (unsigned short*)(ws + O_NUM);
    float* DEN = (float*)(ws + O_DEN);

    const int b = blockIdx.x >> 6;
    const int qt = (blockIdx.x >> 3) & 7;
    const int s = blockIdx.x & 7;
    const int w = threadIdx.x >> 6, lane = threadIdx.x & 63;
    const int low4 = lane & 15, quad = lane >> 4;

    const unsigned short* KSPb = KSP + (size_t)b * 8192 * 64;
    const unsigned short* VTb = VTg + (size_t)b * 64 * 8192;
    const int qbase = qt * 128 + w * 32;

    short8 qa[2][2];
#pragma unroll
    for (int mi = 0; mi < 2; ++mi)
#pragma unroll
      for (int ks = 0; ks < 2; ++ks) {
        short8 qr = *(const short8*)(QT + ((size_t)(b * 1024 + qbase + mi * 16 + low4)) * 64 + ks * 32 + quad * 8);
        short8 qs;
#pragma unroll
        for (int j = 0; j < 8; ++j) qs[j] = (short)f2bf(bf2f((unsigned short)qr[j]) * LOG2E);
        qa[mi][ks] = qs;
      }

    f4 accO[2][4];
    float den[2][4];
#pragma unroll
    for (int mi = 0; mi < 2; ++mi)
#pragma unroll
      for (int n = 0; n < 4; ++n) {
        accO[mi][n] = (f4){0.f, 0.f, 0.f, 0.f};
        den[mi][n] = 0.f;
      }

    for (int it = 0; it < 16; ++it) {
      const int kv0 = s * 1024 + it * 64;
      // ---- stage: 512 K-chunks + 512 V-chunks, id = (n<<7)|(ks<<6)|(L<<2)|q
#pragma unroll
      for (int pass = 0; pass < 2; ++pass) {
        const int id = pass * 256 + threadIdx.x;
        const int n = id >> 7, ks = (id >> 6) & 1, L = (id >> 2) & 15, q = id & 3;
        *(short8*)(&Kt[id * 8]) =
            *(const short8*)(KSPb + (size_t)(kv0 + n * 16 + L) * 64 + ks * 32 + q * 8);
        *(short8*)(&Vt[id * 8]) =
            *(const short8*)(VTb + (size_t)(n * 16 + L) * 8192 + kv0 + ks * 32 + q * 8);
      }
      __syncthreads();

      // ---- QK: 16 MFMA, each K-frag feeds both q-tiles
      f4 sS[2][4];
#pragma unroll
      for (int mi = 0; mi < 2; ++mi)
#pragma unroll
        for (int n = 0; n < 4; ++n) sS[mi][n] = (f4){0.f, 0.f, 0.f, 0.f};
#pragma unroll
      for (int ks = 0; ks < 2; ++ks)
#pragma unroll
        for (int n = 0; n < 4; ++n) {
          short8 kb = *(const short8*)(&Kt[((n * 2 + ks) * 64 + low4 * 4 + quad) * 8]);
          sS[0][n] = MFMA16(qa[0][ks], kb, sS[0][n]);
          sS[1][n] = MFMA16(qa[1][ks], kb, sS[1][n]);
        }
      // ---- exp2, denominator, P to LDS (C-layout -> A-layout round trip)
#pragma unroll
      for (int mi = 0; mi < 2; ++mi)
#pragma unroll
        for (int n = 0; n < 4; ++n)
#pragma unroll
          for (int r = 0; r < 4; ++r) {
            float e = exp2fast(sS[mi][n][r]);
            den[mi][r] += e;
            Plds[w][mi * 16 + quad * 4 + r][n * 16 + low4] = f2bf_rz(e);
          }
      // ---- PV: 16 MFMA, each V-frag feeds both q-tiles
#pragma unroll
      for (int ks = 0; ks < 2; ++ks) {
        short8 pa0 = *(const short8*)&Plds[w][low4][ks * 32 + quad * 8];
        short8 pa1 = *(const short8*)&Plds[w][16 + low4][ks * 32 + quad * 8];
#pragma unroll
        for (int n2 = 0; n2 < 4; ++n2) {
          short8 vb = *(const short8*)(&Vt[((n2 * 2 + ks) * 64 + low4 * 4 + quad) * 8]);
          accO[0][n2] = MFMA16(pa0, vb, accO[0][n2]);
          accO[1][n2] = MFMA16(pa1, vb, accO[1][n2]);
        }
      }
      __syncthreads();
    }

    // den: reduce over the 16 kv-col lanes
#pragma unroll
    for (int mi = 0; mi < 2; ++mi)
#pragma unroll
      for (int r = 0; r < 4; ++r)
#pragma unroll
        for (int o = 1; o < 16; o <<= 1) den[mi][r] += __shfl_xor(den[mi][r], o, 64);

    // partial stores: NUM bf16, DEN f32
#pragma unroll
    for (int mi = 0; mi < 2; ++mi)
#pragma unroll
      for (int r = 0; r < 4; ++r) {
        const int row = qbase + mi * 16 + quad * 4 + r;
#pragma unroll
        for (int n2 = 0; n2 < 4; ++n2)
          NUM[(((size_t)(b * 1024 + row)) * 8 + s) * 64 + n2 * 16 + low4] = f2bf(accO[mi][n2][r]);
        if (low4 == 0) DEN[((size_t)(b * 1024 + row)) * 8 + s] = den[mi][r];
      }
    return;
  }

  // ---- chan_soft: sum 8 partials, max-sub, exp2, normalize -> P ----
  {
    const float* Sp = (const float*)(ws + O_SP);
    unsigned short* P = (unsigned short*)(ws + O_PCH);
    const int bid = blockIdx.x - 512;
    const int b = bid >> 2, rt = bid & 3;
    const int row = rt * 16 + (threadIdx.x >> 4), tc = threadIdx.x & 15;

    float sv[32];
    float mx = -1e30f;
#pragma unroll
    for (int jj = 0; jj < 32; ++jj) {
      const int col = jj * 16 + tc;
      size_t base = ((size_t)b * 64 + row) * 512 + col;
      float v = 0.f;
#pragma unroll
      for (int kt = 0; kt < 8; ++kt) v += Sp[base + (size_t)kt * 262144];
      sv[jj] = v;
      mx = fmaxf(mx, v);
    }
#pragma unroll
    for (int o = 1; o < 16; o <<= 1) mx = fmaxf(mx, __shfl_xor(mx, o, 64));
    float sum = 0.f;
#pragma unroll
    for (int jj = 0; jj < 32; ++jj) {
      float e = exp2fast(sv[jj] - mx);
      sv[jj] = e;
      sum += e;
    }
#pragma unroll
    for (int o = 1; o < 16; o <<= 1) sum += __shfl_xor(sum, o, 64);
    const float rs = 1.0f / sum;
#pragma unroll
    for (int jj = 0; jj < 32; ++jj)
      P[((size_t)b * 64 + row) * 512 + jj * 16 + tc] = f2bf(sv[jj] * rs);
  }
}

// ============================================================================
// K3: spat_fin (256 blocks) ∪ chan_B (128 blocks)
// ============================================================================
__global__ __launch_bounds__(256) void k3_fin_chanB(char* __restrict__ ws)
{
  const unsigned short* QT = (const unsigned short*)(ws + O_QT);

  if (blockIdx.x < 256) {                // ---- spat_fin: 8 bf16 partials ----
    const unsigned short* NUM = (const unsigned short*)(ws + O_NUM);
    const float* DEN = (const float*)(ws + O_DEN);
    unsigned short* Xs = (unsigned short*)(ws + O_XS);

    const unsigned i = blockIdx.x * 256u + threadIdx.x;   // 65536
    const int c0 = (i & 7) * 8;
    const unsigned row = i >> 3;                          // [0, 8192)

    float4 d0 = *(const float4*)(DEN + (size_t)row * 8);
    float4 d1 = *(const float4*)(DEN + (size_t)row * 8 + 4);
    float rd = 1.0f / (d0.x + d0.y + d0.z + d0.w + d1.x + d1.y + d1.z + d1.w);

    float n8[8] = {0, 0, 0, 0, 0, 0, 0, 0};
#pragma unroll
    for (int s = 0; s < 8; ++s) {
      short8 pv = *(const short8*)(NUM + ((size_t)row * 8 + s) * 64 + c0);
#pragma unroll
      for (int j = 0; j < 8; ++j) n8[j] += bf2f((unsigned short)pv[j]);
    }
    size_t ob = (size_t)row * 64 + c0;
    short8 qv = *(const short8*)(QT + ob);
    short8 o8;
#pragma unroll
    for (int j = 0; j < 8; ++j)
      o8[j] = (short)f2bf(n8[j] * rd + bf2f((unsigned short)qv[j]));
    *(short8*)(Xs + ob) = o8;
    return;
  }

  // ---- chan_B: O = P @ Vc + residual ----
  {
    const unsigned short* P = (const unsigned short*)(ws + O_PCH);
    const unsigned short* Vct = (const unsigned short*)(ws + O_VCT);
    unsigned short* Xc = (unsigned short*)(ws + O_XC);

    const int bid = blockIdx.x - 256;
    const int b = bid >> 4, pt = bid & 15;
    const int w = threadIdx.x >> 6, lane = threadIdx.x & 63;
    const int low4 = lane & 15, quad = lane >> 4;
    const int p = pt * 64 + w * 16 + low4;

    f4 acc[4];
#pragma unroll
    for (int m = 0; m < 4; ++m) acc[m] = (f4){0.f, 0.f, 0.f, 0.f};

    for (int ks = 0; ks < 16; ++ks) {
      short8 vb = *(const short8*)(Vct + ((size_t)(b * 1024 + p)) * 512 + ks * 32 + quad * 8);
#pragma unroll
      for (int m = 0; m < 4; ++m) {
        short8 a = *(const short8*)(P + ((size_t)(b * 64 + m * 16 + low4)) * 512 + ks * 32 + quad * 8);
        acc[m] = MFMA16(a, vb, acc[m]);
      }
    }
#pragma unroll
    for (int m = 0; m < 4; ++m)
#pragma unroll
      for (int r = 0; r < 4; ++r) {
        const int c = m * 16 + quad * 4 + r;
        size_t o = ((size_t)(b * 1024 + p)) * 64 + c;
        Xc[o] = f2bf(acc[m][r] + bf2f(QT[o]));
      }
  }
}

// ============================================================================
// K4: conv 5x5 + bias + LN stats.  512 blocks = (s:2)x(b:8)x(pt:32 of 32px),
// 256 thr: wave = (half: off 0..12|13..24) x (wsub: 16-px).  half1 -> LDS.
// ============================================================================
__global__ __launch_bounds__(256) void k4_conv5(char* __restrict__ ws,
                                                const float* __restrict__ sb1,
                                                const float* __restrict__ cb1)
{
  const int id = blockIdx.x;
  const int s = id >> 8, b = (id >> 5) & 7, pt = id & 31;
  const int w = threadIdx.x >> 6, lane = threadIdx.x & 63;
  const int low4 = lane & 15, quad = lane >> 4;
  const int wsub = w & 1, half = w >> 1;

  const unsigned short* X = (const unsigned short*)(ws + (s ? O_XC : O_XS));
  const unsigned short* W1t = (const unsigned short*)(ws + O_W1T);
  unsigned short* Yt = (unsigned short*)(ws + O_YT);
  float* stats = (float*)(ws + O_STATS);
  const float* b1p = s ? cb1 : sb1;

  __shared__ float Hbuf[2][16][65];
  __shared__ float red[2][2];

  const int p = pt * 32 + wsub * 16 + low4;
  const int y0 = p >> 5, x0 = p & 31;

  f4 acc[4];
#pragma unroll
  for (int m = 0; m < 4; ++m) acc[m] = (f4){0.f, 0.f, 0.f, 0.f};

  const int o0 = half ? 13 : 0, o1 = half ? 25 : 13;
  for (int off = o0; off < o1; ++off) {
    const int dy = off / 5 - 2, dx = off % 5 - 2;
    const int ys = y0 + dy, xs = x0 + dx;
    const bool valid = ((unsigned)ys < 32u) & ((unsigned)xs < 32u);
    const int psrc = valid ? (p + dy * 32 + dx) : p;
    const unsigned short* xp = X + ((size_t)(b * 1024 + psrc)) * 64;
    const unsigned short* wp = W1t + ((size_t)((s * 25 + off) * 64)) * 64;
#pragma unroll
    for (int ks = 0; ks < 2; ++ks) {
      short8 bv = *(const short8*)(xp + ks * 32 + quad * 8);
      if (!valid) bv = (short8)0;
#pragma unroll
      for (int m = 0; m < 4; ++m) {
        short8 av = *(const short8*)(wp + (m * 16 + low4) * 64 + ks * 32 + quad * 8);
        acc[m] = MFMA16(av, bv, acc[m]);
      }
    }
  }

  if (half) {
#pragma unroll
    for (int m = 0; m < 4; ++m)
#pragma unroll
      for (int r = 0; r < 4; ++r)
        Hbuf[wsub][low4][m * 16 + quad * 4 + r] = acc[m][r];
  }
  __syncthreads();
  if (!half) {
    float ls = 0.f, ls2 = 0.f;
#pragma unroll
    for (int m = 0; m < 4; ++m)
#pragma unroll
      for (int r = 0; r < 4; ++r) {
        const int co = m * 16 + quad * 4 + r;
        float y = acc[m][r] + Hbuf[wsub][low4][co] + b1p[co];
        Yt[((size_t)((s * 8 + b) * 1024 + p)) * 64 + co] = f2bf(y);
        ls += y; ls2 += y * y;
      }
#pragma unroll
    for (int o = 1; o < 64; o <<= 1) {
      ls += __shfl_xor(ls, o, 64);
      ls2 += __shfl_xor(ls2, o, 64);
    }
    if (lane == 0) { red[0][wsub] = ls; red[1][wsub] = ls2; }
  }
  __syncthreads();
  if (threadIdx.x == 0) {
    atomicAdd(&stats[(s * 8 + b) * 2 + 0], red[0][0] + red[0][1]);
    atomicAdd(&stats[(s * 8 + b) * 2 + 1], red[1][0] + red[1][1]);
  }
}

// ============================================================================
// K5: LN + ReLU + 1x1 conv epilogue.  256 blocks = (s:2)x(b:8)x(pt:16).
// ============================================================================
__global__ __launch_bounds__(256) void k5_final(char* __restrict__ ws,
                                                const float* __restrict__ slnw,
                                                const float* __restrict__ slnb,
                                                const float* __restrict__ clnw,
                                                const float* __restrict__ clnb,
                                                const float* __restrict__ sb2,
                                                const float* __restrict__ cb2,
                                                float* __restrict__ out)
{
  const int id = blockIdx.x;
  const int s = id >> 7, b = (id >> 4) & 7, pt = id & 15;
  const int w = threadIdx.x >> 6, lane = threadIdx.x & 63;
  const int low4 = lane & 15, quad = lane >> 4;
  const int p2 = pt * 64 + w * 16 + low4;

  const unsigned short* Yt = (const unsigned short*)(ws + O_YT);
  const unsigned short* W2b = (const unsigned short*)(ws + O_W2B);
  const float* stats = (const float*)(ws + O_STATS);
  const float* lw = s ? clnw : slnw;
  const float* lb = s ? clnb : slnb;
  const float* b2p = s ? cb2 : sb2;

  const float inv = 1.0f / 65536.0f;
  const float mu = stats[(s * 8 + b) * 2 + 0] * inv;
  const float ms = stats[(s * 8 + b) * 2 + 1] * inv;
  const float rsig = rsqrtf(ms - mu * mu + 1e-5f);

  f4 acc[8];
#pragma unroll
  for (int m = 0; m < 8; ++m) acc[m] = (f4){0.f, 0.f, 0.f, 0.f};

#pragma unroll
  for (int ks = 0; ks < 2; ++ks) {
    size_t yo = ((size_t)((s * 8 + b) * 1024 + p2)) * 64 + ks * 32 + quad * 8;
    short8 yv = *(const short8*)(Yt + yo);
    short8 zv;
#pragma unroll
    for (int j = 0; j < 8; ++j) {
      const int c = ks * 32 + quad * 8 + j;
      float z = (bf2f((unsigned short)yv[j]) - mu) * rsig * lw[c * 1024 + p2] + lb[c * 1024 + p2];
      zv[j] = (short)f2bf(fmaxf(z, 0.f));
    }
#pragma unroll
    for (int m = 0; m < 8; ++m) {
      short8 a = *(const short8*)(W2b + ((size_t)(s * 128 + m * 16 + low4)) * 64 + ks * 32 + quad * 8);
      acc[m] = MFMA16(a, zv, acc[m]);
    }
  }
#pragma unroll
  for (int m = 0; m < 8; ++m)
#pragma unroll
    for (int r = 0; r < 4; ++r) {
      const int nh = m * 16 + quad * 4 + r;
      out[((size_t)((s * 8 + b) * 128 + nh)) * 1024 + p2] = acc[m][r] + b2p[nh];
    }
}

extern "C" void kernel_launch(void* const* d_in, const int* in_sizes, int n_in,
                              void* d_out, int out_size, void* d_ws, size_t ws_size,
                              hipStream_t stream)
{
  const float* q    = (const float*)d_in[0];
  const float* keys = (const float*)d_in[1];
  const float* vals = (const float*)d_in[2];
  const float* sw1  = (const float*)d_in[3];
  const float* sb1  = (const float*)d_in[4];
  const float* slnw = (const float*)d_in[5];
  const float* slnb = (const float*)d_in[6];
  const float* sw2  = (const float*)d_in[7];
  const float* sb2  = (const float*)d_in[8];
  const float* cw1  = (const float*)d_in[9];
  const float* cb1  = (const float*)d_in[10];
  const float* clnw = (const float*)d_in[11];
  const float* clnb = (const float*)d_in[12];
  const float* cw2  = (const float*)d_in[13];
  const float* cb2  = (const float*)d_in[14];
  char* ws = (char*)d_ws;

  hipMemsetAsync(ws + O_STATS, 0, 256, stream);
  k1_prep_chanS<<<3552, 256, 0, stream>>>(q, keys, vals, sw1, sw2, cw1, cw2, ws);
  k2_spat_soft<<<544, 256, 0, stream>>>(ws);
  k3_fin_chanB<<<384, 256, 0, stream>>>(ws);
  k4_conv5<<<512, 256, 0, stream>>>(ws, sb1, cb1);
  k5_final<<<256, 256, 0, stream>>>(ws, slnw, slnb, clnw, clnb, sb2, cb2, (float*)d_out);
}

// Round 5
// 232.248 us; speedup vs baseline: 1.4860x; 1.0155x over previous
//
#include <hip/hip_runtime.h>

// ---------------------------------------------------------------------------
// DualAttention on MI355X.  B=8 L=8 C=64 W=32 (WH=1024, LWH=8192) NH=128 FS=5
// R5: spat_attn = lane-linear LDS frags + global_load_lds dbuf + M=4 + den-MFMA.
//  - K/V tiles staged in A/B-frag lane-linear chunk order via async DMA.
//  - P tile XOR-swizzled (c' = c ^ 2*((row>>2)&3)): free writes, optimal reads.
//  - den computed by MFMA vs ones-vector (no VALU adds, no end shuffle).
//  - LOG2E folded into KSP at prep.  NUM partials bf16, 16-way kv split.
//  - k5 reads pre-transposed bf16 LN params; k4 at 16 waves/CU; VCT deleted.
// ---------------------------------------------------------------------------

#define LOG2E 1.44269504088896340736f

typedef __attribute__((ext_vector_type(8))) short short8;   // bf16 x8 frag
typedef __attribute__((ext_vector_type(4))) float f4;       // fp32 x4 frag

#define MFMA16(a, b, c) __builtin_amdgcn_mfma_f32_16x16x32_bf16(a, b, c, 0, 0, 0)

#define GLOAD_LDS16(gp, lp) __builtin_amdgcn_global_load_lds( \
    (const __attribute__((address_space(1))) void*)(gp), \
    (__attribute__((address_space(3))) void*)(lp), 16, 0, 0)

__device__ __forceinline__ unsigned short f2bf(float f) {   // RNE float->bf16
  union { float f; unsigned u; } v; v.f = f;
  unsigned r = v.u + 0x7FFFu + ((v.u >> 16) & 1u);
  return (unsigned short)(r >> 16);
}
__device__ __forceinline__ unsigned short f2bf_rz(float f) { // truncate (P only)
  union { float f; unsigned u; } v; v.f = f;
  return (unsigned short)(v.u >> 16);
}
__device__ __forceinline__ float bf2f(unsigned short h) {
  union { unsigned u; float f; } v; v.u = ((unsigned)h) << 16;
  return v.f;
}
__device__ __forceinline__ float exp2fast(float x) {
#if __has_builtin(__builtin_amdgcn_exp2f)
  return __builtin_amdgcn_exp2f(x);
#else
  return exp2f(x);
#endif
}

// ---------------- workspace layout (bytes), total ~45.0MB ------------------
#define O_STATS 0ul                      // [2][8][2] f32 (memset 0)
#define O_W1T   256ul                    // [2][25][64][64] bf16
#define O_W2B   409856ul                 // [2][128][64] bf16
#define O_LNW   442624ul                 // [2][1024][64] bf16 (transposed lnw)
#define O_LNB   704768ul                 // [2][1024][64] bf16
#define O_QT    966912ul                 // [8][1024][64] bf16  q^T
#define O_KSP   2015488ul                // [8][8192][64] bf16  spatial K *LOG2E
#define O_VT    10404096ul               // [8][64][8192] bf16  spatial V^T
#define O_NUM   18792704ul               // [8][1024][16][64] bf16 spat num part
#define O_DEN   35569920ul               // [8][1024][16] f32      spat den part
#define O_SP    36094208ul               // [4][8][64][512] f32 chan S partials
#define O_PCH   40288512ul               // [8][64][512] bf16   chan P
#define O_XS    40812800ul               // [8][1024][64] bf16 stem in (spatial)
#define O_XC    41861376ul               // [8][1024][64] bf16 stem in (channel)
#define O_YT    42909952ul               // [2][8][1024][64] bf16 conv1 out

// ============================================================================
// K1: prep (tile transposes + LN transposes + weights) ∪ chan_S (k-split 4)
//   0..1023 keys->KSP(T, *LOG2E); 1024..2047 values->VT(identity);
//   2048..2175 q->QT(T); 2176..2239 ln params(T); 2240..3103 weights;
//   3104..3359 chan_S.
// ============================================================================
__global__ __launch_bounds__(256) void k1_prep_chanS(
    const float* __restrict__ q, const float* __restrict__ keys,
    const float* __restrict__ values,
    const float* __restrict__ sw1, const float* __restrict__ slnw,
    const float* __restrict__ slnb, const float* __restrict__ sw2,
    const float* __restrict__ cw1, const float* __restrict__ clnw,
    const float* __restrict__ clnb, const float* __restrict__ cw2,
    char* __restrict__ ws)
{
  __shared__ float T[64][65];
  const int job = blockIdx.x, t = threadIdx.x;

  if (job < 2240) {                      // ---- tile jobs ----
    int kind, mat = 0, sel = 0;
    if (job < 1024)      { kind = 0; mat = job >> 4; }
    else if (job < 2048) { kind = 1; mat = (job - 1024) >> 4; }
    else if (job < 2176) { kind = 2; mat = (job - 2048) >> 4; }
    else                 { kind = 3; sel = (job - 2176) >> 4; }
    const int pt = job & 15, p0 = pt * 64;
    const float* src =
        kind == 0 ? keys : kind == 1 ? values : kind == 2 ? q
        : (sel == 0 ? slnw : sel == 1 ? slnb : sel == 2 ? clnw : clnb);
    src += (size_t)mat * 65536;

    const int r0 = t >> 4, c4 = (t & 15) * 4;
    if (kind == 1) {                     // identity only: V^T[b][c][l*1024+p]
      unsigned short* VTp = (unsigned short*)(ws + O_VT);
      const int b = mat >> 3, l = mat & 7;
#pragma unroll
      for (int pass = 0; pass < 4; ++pass) {
        const int r = pass * 16 + r0;
        float4 v = *(const float4*)(src + (size_t)r * 1024 + p0 + c4);
        ushort4 o;
        o.x = f2bf(v.x); o.y = f2bf(v.y); o.z = f2bf(v.z); o.w = f2bf(v.w);
        *(ushort4*)(VTp + ((size_t)b * 64 + r) * 8192 + l * 1024 + p0 + c4) = o;
      }
      return;
    }
#pragma unroll
    for (int pass = 0; pass < 4; ++pass) {
      const int r = pass * 16 + r0;
      float4 v = *(const float4*)(src + (size_t)r * 1024 + p0 + c4);
      T[r][c4] = v.x; T[r][c4 + 1] = v.y; T[r][c4 + 2] = v.z; T[r][c4 + 3] = v.w;
    }
    __syncthreads();
#pragma unroll
    for (int pass = 0; pass < 2; ++pass) {
      const int p = pass * 32 + (t >> 3), cs = (t & 7) * 8;
      short8 o;
      if (kind == 0) {                   // Ksp[b][l*1024+p][c] * LOG2E
#pragma unroll
        for (int j = 0; j < 8; ++j) o[j] = (short)f2bf(T[cs + j][p] * LOG2E);
        const int b = mat >> 3, l = mat & 7;
        *(short8*)((unsigned short*)(ws + O_KSP) +
                   ((size_t)b * 8192 + l * 1024 + p0 + p) * 64 + cs) = o;
      } else if (kind == 2) {            // Qt[b][p][c]
#pragma unroll
        for (int j = 0; j < 8; ++j) o[j] = (short)f2bf(T[cs + j][p]);
        *(short8*)((unsigned short*)(ws + O_QT) +
                   ((size_t)mat * 1024 + p0 + p) * 64 + cs) = o;
      } else {                           // LN param^T [s][p][c]
#pragma unroll
        for (int j = 0; j < 8; ++j) o[j] = (short)f2bf(T[cs + j][p]);
        unsigned long off = (sel & 1) ? O_LNB : O_LNW;
        *(short8*)((unsigned short*)(ws + off) +
                   ((size_t)(sel >> 1) * 1024 + p0 + p) * 64 + cs) = o;
      }
    }
    return;
  }

  if (job < 3104) {                      // ---- weights ----
    unsigned i = (job - 2240) * 256u + t;
    if (i < 204800u) {                   // W1t[s][off][co][ci] <- w1[co][ci][off]
      unsigned ci = i & 63u, co = (i >> 6) & 63u, tt = i >> 12;
      unsigned off = tt % 25u, st = tt / 25u;
      const float* w = st ? cw1 : sw1;
      ((unsigned short*)(ws + O_W1T))[i] = f2bf(w[(co * 64u + ci) * 25u + off]);
      return;
    }
    i -= 204800u;
    if (i < 16384u) {                    // W2b[s][nh][c]
      unsigned c = i & 63u, nh = (i >> 6) & 127u, st = i >> 13;
      const float* w = st ? cw2 : sw2;
      ((unsigned short*)(ws + O_W2B))[i] = f2bf(w[nh * 64u + c]);
    }
    return;
  }

  // ---- chan_S: 256 blocks = (b:8) x (colT:8 of 64 cols) x (kt:4 of 256 ch)
  {
    float* Sp = (float*)(ws + O_SP);
    const int bid = job - 3104;
    const int b = bid >> 5, colT = (bid >> 2) & 7, kt = bid & 3;
    const int w = t >> 6, lane = t & 63;
    const int low4 = lane & 15, quad = lane >> 4;
    const int col0 = colT * 64 + w * 16;

    f4 acc[4];
#pragma unroll
    for (int m = 0; m < 4; ++m) acc[m] = (f4){0.f, 0.f, 0.f, 0.f};

#pragma unroll
    for (int kst = 0; kst < 8; ++kst) {
      const int k = kt * 256 + kst * 32 + quad * 8;
      const float* kp = keys + ((size_t)(b * 512 + col0 + low4)) * 1024 + k;
      float4 u0 = *(const float4*)kp;
      float4 u1 = *(const float4*)(kp + 4);
      float kv[8] = {u0.x, u0.y, u0.z, u0.w, u1.x, u1.y, u1.z, u1.w};
      short8 bh, bl;
#pragma unroll
      for (int j = 0; j < 8; ++j) {
        unsigned short hi = f2bf(kv[j]);
        bh[j] = (short)hi;
        bl[j] = (short)f2bf(kv[j] - bf2f(hi));
      }
#pragma unroll
      for (int m = 0; m < 4; ++m) {
        const float* qp = q + ((size_t)(b * 64 + m * 16 + low4)) * 1024 + k;
        float4 w0 = *(const float4*)qp;
        float4 w1 = *(const float4*)(qp + 4);
        float qv[8] = {w0.x, w0.y, w0.z, w0.w, w1.x, w1.y, w1.z, w1.w};
        short8 ah, al;
#pragma unroll
        for (int j = 0; j < 8; ++j) {
          float sv = qv[j] * LOG2E;
          unsigned short hi = f2bf(sv);
          ah[j] = (short)hi;
          al[j] = (short)f2bf(sv - bf2f(hi));
        }
        acc[m] = MFMA16(ah, bh, acc[m]);
        acc[m] = MFMA16(al, bh, acc[m]);
        acc[m] = MFMA16(ah, bl, acc[m]);
      }
    }
#pragma unroll
    for (int m = 0; m < 4; ++m)
#pragma unroll
      for (int r = 0; r < 4; ++r)
        Sp[(((size_t)kt * 8 + b) * 64 + m * 16 + quad * 4 + r) * 512 + col0 + low4] = acc[m][r];
  }
}

// ============================================================================
// K2: spat_attn (512 blocks) ∪ chan_soft (32 blocks)
// spat: block = (b:8)x(qt:4 of 256 q-rows)x(s:16 kv-sixteenths of 512).
//   4 waves, M=4 (wave owns 64 q-rows).  Per iter (64 kv): K/V staged via
//   global_load_lds into lane-linear frag chunks (dbuf, 1 barrier/iter);
//   QK 32 MFMA -> exp2 -> P (XOR-swizzled LDS) -> PV 32 MFMA + 8 den-MFMA.
// ============================================================================
__global__ __launch_bounds__(256, 2) void k2_spat_soft(char* __restrict__ ws)
{
  __shared__ __align__(16) unsigned short Kt[2][4096];   // 16KB dbuf
  __shared__ __align__(16) unsigned short Vt[2][4096];   // 16KB dbuf
  __shared__ __align__(16) unsigned short Pl[4][4096];   // 32KB (8KB/wave)

  if (blockIdx.x < 512) {
    const unsigned short* QT = (const unsigned short*)(ws + O_QT);
    const unsigned short* KSP = (const unsigned short*)(ws + O_KSP);
    const unsigned short* VTg = (const unsigned short*)(ws + O_VT);
    unsigned short* NUM = (unsigned short*)(ws + O_NUM);
    float* DEN = (float*)(ws + O_DEN);

    const int b = blockIdx.x >> 6;
    const int qt = (blockIdx.x >> 4) & 3;
    const int s = blockIdx.x & 15;
    const int t = threadIdx.x;
    const int w = t >> 6, lane = t & 63;
    const int low4 = lane & 15, quad = lane >> 4;

    const unsigned short* KSPb = KSP + (size_t)b * 8192 * 64;
    const unsigned short* VTb = VTg + (size_t)b * 64 * 8192;
    const int qbase = qt * 256 + w * 64;
    const int kvbase = s * 512;

    // staging decode for this thread's two chunks (c = t, t+256)
    int cn[2], cks[2], cqd[2], cl4[2];
#pragma unroll
    for (int pass = 0; pass < 2; ++pass) {
      const int c = pass * 256 + t;
      cn[pass] = c >> 7; cks[pass] = (c >> 6) & 1;
      cqd[pass] = (c >> 4) & 3; cl4[pass] = c & 15;
    }

    // Q fragments (pre-scaled K carries LOG2E)
    short8 qa[4][2];
#pragma unroll
    for (int mi = 0; mi < 4; ++mi)
#pragma unroll
      for (int ks = 0; ks < 2; ++ks)
        qa[mi][ks] = *(const short8*)(QT +
            ((size_t)(b * 1024 + qbase + mi * 16 + low4)) * 64 + ks * 32 + quad * 8);

    short8 vones;
#pragma unroll
    for (int j = 0; j < 8; ++j) vones[j] = (short)0x3F80;

    f4 accO[4][4], accD[4];
#pragma unroll
    for (int m = 0; m < 4; ++m) {
      accD[m] = (f4){0.f, 0.f, 0.f, 0.f};
#pragma unroll
      for (int n = 0; n < 4; ++n) accO[m][n] = (f4){0.f, 0.f, 0.f, 0.f};
    }

    // issue stage for iter 0 into buf 0
#pragma unroll
    for (int pass = 0; pass < 2; ++pass) {
      const int kv0 = kvbase;
      GLOAD_LDS16(KSPb + ((size_t)(kv0 + cn[pass] * 16 + cl4[pass])) * 64 +
                      cks[pass] * 32 + cqd[pass] * 8,
                  &Kt[0][(pass * 256 + w * 64) * 8]);
      GLOAD_LDS16(VTb + ((size_t)(cn[pass] * 16 + cl4[pass])) * 8192 + kv0 +
                      cks[pass] * 32 + cqd[pass] * 8,
                  &Vt[0][(pass * 256 + w * 64) * 8]);
    }

    const int pswz = ((low4 >> 2) & 3) << 1;      // read-side swizzle key
    for (int it = 0; it < 8; ++it) {
      const int d = it & 1;
      __syncthreads();                   // drains vmcnt -> buf d ready
      if (it < 7) {                      // prefetch next iter into other buf
        const int kv1 = kvbase + (it + 1) * 64;
#pragma unroll
        for (int pass = 0; pass < 2; ++pass) {
          GLOAD_LDS16(KSPb + ((size_t)(kv1 + cn[pass] * 16 + cl4[pass])) * 64 +
                          cks[pass] * 32 + cqd[pass] * 8,
                      &Kt[d ^ 1][(pass * 256 + w * 64) * 8]);
          GLOAD_LDS16(VTb + ((size_t)(cn[pass] * 16 + cl4[pass])) * 8192 + kv1 +
                          cks[pass] * 32 + cqd[pass] * 8,
                      &Vt[d ^ 1][(pass * 256 + w * 64) * 8]);
        }
      }
      // ---- QK + exp2 + P, one 16-col block at a time (low VGPR) ----
#pragma unroll
      for (int n = 0; n < 4; ++n) {
        f4 sS[4];
#pragma unroll
        for (int mi = 0; mi < 4; ++mi) sS[mi] = (f4){0.f, 0.f, 0.f, 0.f};
#pragma unroll
        for (int ks = 0; ks < 2; ++ks) {
          short8 kb = *(const short8*)&Kt[d][((n * 2 + ks) * 64 + lane) * 8];
#pragma unroll
          for (int mi = 0; mi < 4; ++mi) sS[mi] = MFMA16(qa[mi][ks], kb, sS[mi]);
        }
        const int cpr = (((n * 2 + (low4 >> 3)) ^ (quad << 1)) << 3) + (low4 & 7);
#pragma unroll
        for (int mi = 0; mi < 4; ++mi) {
          unsigned short* pw = &Pl[w][(mi * 16 + quad * 4) * 64 + cpr];
#pragma unroll
          for (int r = 0; r < 4; ++r)
            pw[r * 64] = f2bf_rz(exp2fast(sS[mi][r]));
        }
      }
      // ---- PV + den (MFMA vs ones) ----
#pragma unroll
      for (int ks = 0; ks < 2; ++ks) {
        short8 vb[4];
#pragma unroll
        for (int n2 = 0; n2 < 4; ++n2)
          vb[n2] = *(const short8*)&Vt[d][((n2 * 2 + ks) * 64 + lane) * 8];
        const int cr = (((ks * 4 + quad) ^ pswz) << 3);
#pragma unroll
        for (int m = 0; m < 4; ++m) {
          short8 pa = *(const short8*)&Pl[w][(m * 16 + low4) * 64 + cr];
          accD[m] = MFMA16(pa, vones, accD[m]);
#pragma unroll
          for (int n2 = 0; n2 < 4; ++n2) accO[m][n2] = MFMA16(pa, vb[n2], accO[m][n2]);
        }
      }
    }

    // partial stores: NUM bf16, DEN f32 (accD cols all equal = row-sum)
#pragma unroll
    for (int m = 0; m < 4; ++m)
#pragma unroll
      for (int r = 0; r < 4; ++r) {
        const int row = qbase + m * 16 + quad * 4 + r;
        const size_t base = ((size_t)(b * 1024 + row) * 16 + s);
#pragma unroll
        for (int n2 = 0; n2 < 4; ++n2)
          NUM[base * 64 + n2 * 16 + low4] = f2bf(accO[m][n2][r]);
        if (low4 == 0) DEN[base] = accD[m][r];
      }
    return;
  }

  // ---- chan_soft: sum 4 partials, max-sub, exp2, normalize -> P ----
  {
    const float* Sp = (const float*)(ws + O_SP);
    unsigned short* P = (unsigned short*)(ws + O_PCH);
    const int bid = blockIdx.x - 512;
    const int b = bid >> 2, rt = bid & 3;
    const int row = rt * 16 + (threadIdx.x >> 4), tc = threadIdx.x & 15;

    float sv[32];
    float mx = -1e30f;
#pragma unroll
    for (int jj = 0; jj < 32; ++jj) {
      const int col = jj * 16 + tc;
      size_t base = ((size_t)b * 64 + row) * 512 + col;
      float v = Sp[base] + Sp[base + 262144] + Sp[base + 524288] + Sp[base + 786432];
      sv[jj] = v;
      mx = fmaxf(mx, v);
    }
#pragma unroll
    for (int o = 1; o < 16; o <<= 1) mx = fmaxf(mx, __shfl_xor(mx, o, 64));
    float sum = 0.f;
#pragma unroll
    for (int jj = 0; jj < 32; ++jj) {
      float e = exp2fast(sv[jj] - mx);
      sv[jj] = e;
      sum += e;
    }
#pragma unroll
    for (int o = 1; o < 16; o <<= 1) sum += __shfl_xor(sum, o, 64);
    const float rs = 1.0f / sum;
#pragma unroll
    for (int jj = 0; jj < 32; ++jj)
      P[((size_t)b * 64 + row) * 512 + jj * 16 + tc] = f2bf(sv[jj] * rs);
  }
}

// ============================================================================
// K3: spat_fin (512 blocks, 4 ch/thread) ∪ chan_B (128 blocks, raw-V gather)
// ============================================================================
__global__ __launch_bounds__(256) void k3_fin_chanB(const float* __restrict__ values,
                                                    char* __restrict__ ws)
{
  const unsigned short* QT = (const unsigned short*)(ws + O_QT);

  if (blockIdx.x < 512) {                // ---- spat_fin: 16 bf16 partials ----
    const unsigned short* NUM = (const unsigned short*)(ws + O_NUM);
    const float* DEN = (const float*)(ws + O_DEN);
    unsigned short* Xs = (unsigned short*)(ws + O_XS);

    const unsigned i = blockIdx.x * 256u + threadIdx.x;   // 131072
    const int c0 = (i & 15) * 4;
    const unsigned row = i >> 4;                          // [0, 8192)

    float dtot = 0.f;
#pragma unroll
    for (int sq = 0; sq < 4; ++sq) {
      float4 dv = *(const float4*)(DEN + (size_t)row * 16 + sq * 4);
      dtot += dv.x + dv.y + dv.z + dv.w;
    }
    float n4[4] = {0.f, 0.f, 0.f, 0.f};
#pragma unroll
    for (int s = 0; s < 16; ++s) {
      ushort4 pv = *(const ushort4*)(NUM + ((size_t)row * 16 + s) * 64 + c0);
      n4[0] += bf2f(pv.x); n4[1] += bf2f(pv.y);
      n4[2] += bf2f(pv.z); n4[3] += bf2f(pv.w);
    }
    const float rd = 1.0f / dtot;
    size_t ob = (size_t)row * 64 + c0;
    ushort4 qv = *(const ushort4*)(QT + ob);
    ushort4 o4;
    o4.x = f2bf(n4[0] * rd + bf2f(qv.x));
    o4.y = f2bf(n4[1] * rd + bf2f(qv.y));
    o4.z = f2bf(n4[2] * rd + bf2f(qv.z));
    o4.w = f2bf(n4[3] * rd + bf2f(qv.w));
    *(ushort4*)(Xs + ob) = o4;
    return;
  }

  // ---- chan_B: O = P @ V + residual (V gathered raw f32) ----
  {
    const unsigned short* P = (const unsigned short*)(ws + O_PCH);
    unsigned short* Xc = (unsigned short*)(ws + O_XC);

    const int bid = blockIdx.x - 512;
    const int b = bid >> 4, pt = bid & 15;
    const int w = threadIdx.x >> 6, lane = threadIdx.x & 63;
    const int low4 = lane & 15, quad = lane >> 4;
    const int p = pt * 64 + w * 16 + low4;

    f4 acc[4];
#pragma unroll
    for (int m = 0; m < 4; ++m) acc[m] = (f4){0.f, 0.f, 0.f, 0.f};

    const float* vbase = values + (size_t)b * 524288 + p;
    for (int ks = 0; ks < 16; ++ks) {
      short8 vbv;
      const float* vp = vbase + (size_t)(ks * 32 + quad * 8) * 1024;
#pragma unroll
      for (int j = 0; j < 8; ++j) vbv[j] = (short)f2bf(vp[(size_t)j * 1024]);
#pragma unroll
      for (int m = 0; m < 4; ++m) {
        short8 a = *(const short8*)(P + ((size_t)(b * 64 + m * 16 + low4)) * 512 + ks * 32 + quad * 8);
        acc[m] = MFMA16(a, vbv, acc[m]);
      }
    }
#pragma unroll
    for (int m = 0; m < 4; ++m)
#pragma unroll
      for (int r = 0; r < 4; ++r) {
        const int c = m * 16 + quad * 4 + r;
        size_t o = ((size_t)(b * 1024 + p)) * 64 + c;
        Xc[o] = f2bf(acc[m][r] + bf2f(QT[o]));
      }
  }
}

// ============================================================================
// K4: conv 5x5 + bias + LN stats.  512 blocks x 512 thr = 16 waves/CU.
// (s:2)x(b:8)x(pt:32 of 32px); wave = (quarter:4 of 25 offs) x (wsub:2 of 16px)
// ============================================================================
__global__ __launch_bounds__(512) void k4_conv5(char* __restrict__ ws,
                                                const float* __restrict__ sb1,
                                                const float* __restrict__ cb1)
{
  const int id = blockIdx.x;
  const int s = id >> 8, b = (id >> 5) & 7, pt = id & 31;
  const int t = threadIdx.x;
  const int w = t >> 6, lane = t & 63;
  const int low4 = lane & 15, quad = lane >> 4;
  const int wsub = w & 1, quarter = w >> 1;

  const unsigned short* X = (const unsigned short*)(ws + (s ? O_XC : O_XS));
  const unsigned short* W1t = (const unsigned short*)(ws + O_W1T);
  unsigned short* Yt = (unsigned short*)(ws + O_YT);
  float* stats = (float*)(ws + O_STATS);
  const float* b1p = s ? cb1 : sb1;

  __shared__ float Hbuf[3][2][16][65];
  __shared__ float red[2][2];

  const int p = pt * 32 + wsub * 16 + low4;
  const int y0 = p >> 5, x0 = p & 31;

  f4 acc[4];
#pragma unroll
  for (int m = 0; m < 4; ++m) acc[m] = (f4){0.f, 0.f, 0.f, 0.f};

  const int o0 = quarter == 0 ? 0 : quarter == 1 ? 7 : quarter == 2 ? 13 : 19;
  const int o1 = quarter == 0 ? 7 : quarter == 1 ? 13 : quarter == 2 ? 19 : 25;
  for (int off = o0; off < o1; ++off) {
    const int dy = off / 5 - 2, dx = off % 5 - 2;
    const int ys = y0 + dy, xs = x0 + dx;
    const bool valid = ((unsigned)ys < 32u) & ((unsigned)xs < 32u);
    const int psrc = valid ? (p + dy * 32 + dx) : p;
    const unsigned short* xp = X + ((size_t)(b * 1024 + psrc)) * 64;
    const unsigned short* wp = W1t + ((size_t)((s * 25 + off) * 64)) * 64;
#pragma unroll
    for (int ks = 0; ks < 2; ++ks) {
      short8 bv = *(const short8*)(xp + ks * 32 + quad * 8);
      if (!valid) bv = (short8)0;
#pragma unroll
      for (int m = 0; m < 4; ++m) {
        short8 av = *(const short8*)(wp + (m * 16 + low4) * 64 + ks * 32 + quad * 8);
        acc[m] = MFMA16(av, bv, acc[m]);
      }
    }
  }

  if (quarter) {
#pragma unroll
    for (int m = 0; m < 4; ++m)
#pragma unroll
      for (int r = 0; r < 4; ++r)
        Hbuf[quarter - 1][wsub][low4][m * 16 + quad * 4 + r] = acc[m][r];
  }
  __syncthreads();
  if (!quarter) {
    float ls = 0.f, ls2 = 0.f;
#pragma unroll
    for (int m = 0; m < 4; ++m)
#pragma unroll
      for (int r = 0; r < 4; ++r) {
        const int co = m * 16 + quad * 4 + r;
        float y = acc[m][r] + Hbuf[0][wsub][low4][co] + Hbuf[1][wsub][low4][co] +
                  Hbuf[2][wsub][low4][co] + b1p[co];
        Yt[((size_t)((s * 8 + b) * 1024 + p)) * 64 + co] = f2bf(y);
        ls += y; ls2 += y * y;
      }
#pragma unroll
    for (int o = 1; o < 64; o <<= 1) {
      ls += __shfl_xor(ls, o, 64);
      ls2 += __shfl_xor(ls2, o, 64);
    }
    if (lane == 0) { red[0][wsub] = ls; red[1][wsub] = ls2; }
  }
  __syncthreads();
  if (t == 0) {
    atomicAdd(&stats[(s * 8 + b) * 2 + 0], red[0][0] + red[0][1]);
    atomicAdd(&stats[(s * 8 + b) * 2 + 1], red[1][0] + red[1][1]);
  }
}

// ============================================================================
// K5: LN + ReLU + 1x1 conv.  512 blocks = (s:2)x(b:8)x(pt:32 of 32px);
// wave = (nh-half) x (px-half); LN params pre-transposed bf16.
// ============================================================================
__global__ __launch_bounds__(256) void k5_final(char* __restrict__ ws,
                                                const float* __restrict__ sb2,
                                                const float* __restrict__ cb2,
                                                float* __restrict__ out)
{
  const int id = blockIdx.x;
  const int s = id >> 8, b = (id >> 5) & 7, pt = id & 31;
  const int w = threadIdx.x >> 6, lane = threadIdx.x & 63;
  const int low4 = lane & 15, quad = lane >> 4;
  const int p2 = pt * 32 + (w & 1) * 16 + low4;
  const int nh0 = (w >> 1) * 64;

  const unsigned short* Yt = (const unsigned short*)(ws + O_YT);
  const unsigned short* LNW = (const unsigned short*)(ws + O_LNW);
  const unsigned short* LNB = (const unsigned short*)(ws + O_LNB);
  const unsigned short* W2b = (const unsigned short*)(ws + O_W2B);
  const float* stats = (const float*)(ws + O_STATS);
  const float* b2p = s ? cb2 : sb2;

  const float inv = 1.0f / 65536.0f;
  const float mu = stats[(s * 8 + b) * 2 + 0] * inv;
  const float ms = stats[(s * 8 + b) * 2 + 1] * inv;
  const float rsig = rsqrtf(ms - mu * mu + 1e-5f);

  f4 acc[4];
#pragma unroll
  for (int m = 0; m < 4; ++m) acc[m] = (f4){0.f, 0.f, 0.f, 0.f};

#pragma unroll
  for (int ks = 0; ks < 2; ++ks) {
    size_t yo = ((size_t)((s * 8 + b) * 1024 + p2)) * 64 + ks * 32 + quad * 8;
    size_t lo = ((size_t)(s * 1024 + p2)) * 64 + ks * 32 + quad * 8;
    short8 yv = *(const short8*)(Yt + yo);
    short8 lw8 = *(const short8*)(LNW + lo);
    short8 lb8 = *(const short8*)(LNB + lo);
    short8 zv;
#pragma unroll
    for (int j = 0; j < 8; ++j) {
      float z = (bf2f((unsigned short)yv[j]) - mu) * rsig * bf2f((unsigned short)lw8[j]) +
                bf2f((unsigned short)lb8[j]);
      zv[j] = (short)f2bf(fmaxf(z, 0.f));
    }
#pragma unroll
    for (int m = 0; m < 4; ++m) {
      short8 a = *(const short8*)(W2b + ((size_t)(s * 128 + nh0 + m * 16 + low4)) * 64 + ks * 32 + quad * 8);
      acc[m] = MFMA16(a, zv, acc[m]);
    }
  }
#pragma unroll
  for (int m = 0; m < 4; ++m)
#pragma unroll
    for (int r = 0; r < 4; ++r) {
      const int nh = nh0 + m * 16 + quad * 4 + r;
      out[((size_t)((s * 8 + b) * 128 + nh)) * 1024 + p2] = acc[m][r] + b2p[nh];
    }
}

extern "C" void kernel_launch(void* const* d_in, const int* in_sizes, int n_in,
                              void* d_out, int out_size, void* d_ws, size_t ws_size,
                              hipStream_t stream)
{
  const float* q    = (const float*)d_in[0];
  const float* keys = (const float*)d_in[1];
  const float* vals = (const float*)d_in[2];
  const float* sw1  = (const float*)d_in[3];
  const float* sb1  = (const float*)d_in[4];
  const float* slnw = (const float*)d_in[5];
  const float* slnb = (const float*)d_in[6];
  const float* sw2  = (const float*)d_in[7];
  const float* sb2  = (const float*)d_in[8];
  const float* cw1  = (const float*)d_in[9];
  const float* cb1  = (const float*)d_in[10];
  const float* clnw = (const float*)d_in[11];
  const float* clnb = (const float*)d_in[12];
  const float* cw2  = (const float*)d_in[13];
  const float* cb2  = (const float*)d_in[14];
  char* ws = (char*)d_ws;

  hipMemsetAsync(ws + O_STATS, 0, 256, stream);
  k1_prep_chanS<<<3360, 256, 0, stream>>>(q, keys, vals, sw1, slnw, slnb, sw2,
                                          cw1, clnw, clnb, cw2, ws);
  k2_spat_soft<<<544, 256, 0, stream>>>(ws);
  k3_fin_chanB<<<640, 256, 0, stream>>>(vals, ws);
  k4_conv5<<<512, 512, 0, stream>>>(ws, sb1, cb1);
  k5_final<<<512, 256, 0, stream>>>(ws, sb2, cb2, (float*)d_out);
}

// Round 7
// 211.405 us; speedup vs baseline: 1.6325x; 1.0986x over previous
//
#include <hip/hip_runtime.h>

// ---------------------------------------------------------------------------
// DualAttention on MI355X.  B=8 L=8 C=64 W=32 (WH=1024, LWH=8192) NH=128 FS=5
// R7 (= R6 with compile fixes): 6-kernel pipeline; chan_S rebuilt as
// LDS-staged GEMM (global_load_lds of raw f32 q/keys in frag-chunk order,
// hi/lo split from LDS), fused into K2.
//   K1 transposes+weights | K2 spat_attn ∪ chan_S | K3 spat_fin ∪ chan_soft
//   K4 conv5-spat ∪ chan_B | K5 conv5-chan ∪ final-spat | K6 final-chan
// Fixes vs R6: no LDS pointer array (integer offsets), no min-waves hint.
// ---------------------------------------------------------------------------

#define LOG2E 1.44269504088896340736f

typedef __attribute__((ext_vector_type(8))) short short8;   // bf16 x8 frag
typedef __attribute__((ext_vector_type(4))) float f4;       // fp32 x4 frag

#define MFMA16(a, b, c) __builtin_amdgcn_mfma_f32_16x16x32_bf16(a, b, c, 0, 0, 0)

#define GLOAD_LDS16(gp, lp) __builtin_amdgcn_global_load_lds( \
    (const __attribute__((address_space(1))) void*)(gp), \
    (__attribute__((address_space(3))) void*)(lp), 16, 0, 0)

__device__ __forceinline__ unsigned short f2bf(float f) {   // RNE float->bf16
  union { float f; unsigned u; } v; v.f = f;
  unsigned r = v.u + 0x7FFFu + ((v.u >> 16) & 1u);
  return (unsigned short)(r >> 16);
}
__device__ __forceinline__ unsigned short f2bf_rz(float f) { // truncate (P only)
  union { float f; unsigned u; } v; v.f = f;
  return (unsigned short)(v.u >> 16);
}
__device__ __forceinline__ float bf2f(unsigned short h) {
  union { unsigned u; float f; } v; v.u = ((unsigned)h) << 16;
  return v.f;
}
__device__ __forceinline__ float exp2fast(float x) {
#if __has_builtin(__builtin_amdgcn_exp2f)
  return __builtin_amdgcn_exp2f(x);
#else
  return exp2f(x);
#endif
}

// ---------------- workspace layout (bytes), total ~45.0MB ------------------
#define O_STATS 0ul                      // [2][8][2] f32 (memset 0)
#define O_W1T   256ul                    // [2][25][64][64] bf16
#define O_W2B   409856ul                 // [2][128][64] bf16
#define O_LNW   442624ul                 // [2][1024][64] bf16 (transposed lnw)
#define O_LNB   704768ul                 // [2][1024][64] bf16
#define O_QT    966912ul                 // [8][1024][64] bf16  q^T
#define O_KSP   2015488ul                // [8][8192][64] bf16  spatial K *LOG2E
#define O_VT    10404096ul               // [8][64][8192] bf16  spatial V^T
#define O_NUM   18792704ul               // [8][1024][16][64] bf16 spat num part
#define O_DEN   35569920ul               // [8][1024][16] f32      spat den part
#define O_SP    36094208ul               // [4][8][64][512] f32 chan S partials
#define O_PCH   40288512ul               // [8][64][512] bf16   chan P
#define O_XS    40812800ul               // [8][1024][64] bf16 stem in (spatial)
#define O_XC    41861376ul               // [8][1024][64] bf16 stem in (channel)
#define O_YT    42909952ul               // [2][8][1024][64] bf16 conv1 out

// ============================================================================
// K1: tile transposes + LN transposes + weights.  grid 3104.
// ============================================================================
__global__ __launch_bounds__(256) void k1_prep(
    const float* __restrict__ q, const float* __restrict__ keys,
    const float* __restrict__ values,
    const float* __restrict__ sw1, const float* __restrict__ slnw,
    const float* __restrict__ slnb, const float* __restrict__ sw2,
    const float* __restrict__ cw1, const float* __restrict__ clnw,
    const float* __restrict__ clnb, const float* __restrict__ cw2,
    char* __restrict__ ws)
{
  __shared__ float T[64][65];
  const int job = blockIdx.x, t = threadIdx.x;

  if (job < 2240) {                      // ---- tile jobs ----
    int kind, mat = 0, sel = 0;
    if (job < 1024)      { kind = 0; mat = job >> 4; }
    else if (job < 2048) { kind = 1; mat = (job - 1024) >> 4; }
    else if (job < 2176) { kind = 2; mat = (job - 2048) >> 4; }
    else                 { kind = 3; sel = (job - 2176) >> 4; }
    const int pt = job & 15, p0 = pt * 64;
    const float* src =
        kind == 0 ? keys : kind == 1 ? values : kind == 2 ? q
        : (sel == 0 ? slnw : sel == 1 ? slnb : sel == 2 ? clnw : clnb);
    src += (size_t)mat * 65536;

    const int r0 = t >> 4, c4 = (t & 15) * 4;
    if (kind == 1) {                     // identity only: V^T[b][c][l*1024+p]
      unsigned short* VTp = (unsigned short*)(ws + O_VT);
      const int b = mat >> 3, l = mat & 7;
#pragma unroll
      for (int pass = 0; pass < 4; ++pass) {
        const int r = pass * 16 + r0;
        float4 v = *(const float4*)(src + (size_t)r * 1024 + p0 + c4);
        ushort4 o;
        o.x = f2bf(v.x); o.y = f2bf(v.y); o.z = f2bf(v.z); o.w = f2bf(v.w);
        *(ushort4*)(VTp + ((size_t)b * 64 + r) * 8192 + l * 1024 + p0 + c4) = o;
      }
      return;
    }
#pragma unroll
    for (int pass = 0; pass < 4; ++pass) {
      const int r = pass * 16 + r0;
      float4 v = *(const float4*)(src + (size_t)r * 1024 + p0 + c4);
      T[r][c4] = v.x; T[r][c4 + 1] = v.y; T[r][c4 + 2] = v.z; T[r][c4 + 3] = v.w;
    }
    __syncthreads();
#pragma unroll
    for (int pass = 0; pass < 2; ++pass) {
      const int p = pass * 32 + (t >> 3), cs = (t & 7) * 8;
      short8 o;
      if (kind == 0) {                   // Ksp[b][l*1024+p][c] * LOG2E
#pragma unroll
        for (int j = 0; j < 8; ++j) o[j] = (short)f2bf(T[cs + j][p] * LOG2E);
        const int b = mat >> 3, l = mat & 7;
        *(short8*)((unsigned short*)(ws + O_KSP) +
                   ((size_t)b * 8192 + l * 1024 + p0 + p) * 64 + cs) = o;
      } else if (kind == 2) {            // Qt[b][p][c]
#pragma unroll
        for (int j = 0; j < 8; ++j) o[j] = (short)f2bf(T[cs + j][p]);
        *(short8*)((unsigned short*)(ws + O_QT) +
                   ((size_t)mat * 1024 + p0 + p) * 64 + cs) = o;
      } else {                           // LN param^T [s][p][c]
#pragma unroll
        for (int j = 0; j < 8; ++j) o[j] = (short)f2bf(T[cs + j][p]);
        unsigned long off = (sel & 1) ? O_LNB : O_LNW;
        *(short8*)((unsigned short*)(ws + off) +
                   ((size_t)(sel >> 1) * 1024 + p0 + p) * 64 + cs) = o;
      }
    }
    return;
  }

  // ---- weights ----
  {
    unsigned i = (job - 2240) * 256u + t;
    if (i < 204800u) {                   // W1t[s][off][co][ci] <- w1[co][ci][off]
      unsigned ci = i & 63u, co = (i >> 6) & 63u, tt = i >> 12;
      unsigned off = tt % 25u, st = tt / 25u;
      const float* w = st ? cw1 : sw1;
      ((unsigned short*)(ws + O_W1T))[i] = f2bf(w[(co * 64u + ci) * 25u + off]);
      return;
    }
    i -= 204800u;
    if (i < 16384u) {                    // W2b[s][nh][c]
      unsigned c = i & 63u, nh = (i >> 6) & 127u, st = i >> 13;
      const float* w = st ? cw2 : sw2;
      ((unsigned short*)(ws + O_W2B))[i] = f2bf(w[nh * 64u + c]);
    }
  }
}

// ============================================================================
// K2: spat_attn (blocks 0..511) ∪ chan_S (512..639)
// spat: as R5 (M=4, lane-linear frag staging, dbuf, den-MFMA, kv-split 16).
// chan_S: (b:8)x(colT:4 of 128 cols)x(kt:4 of 256 k).  Per iter (32 k):
//   stage raw f32 K-tile[128x32] + Q-tile[64x32] via global_load_lds into
//   frag-chunk order (dbuf 48KB); hi/lo split from LDS; 24 MFMA/wave/iter.
// ============================================================================
__global__ __launch_bounds__(256) void k2_spat_chanS(
    const float* __restrict__ q, const float* __restrict__ keys,
    char* __restrict__ ws)
{
  __shared__ __align__(16) unsigned char SM[65536];

  if (blockIdx.x < 512) {                // ================= spatial =========
    unsigned short (*Kt)[4096] = (unsigned short(*)[4096])(SM);
    unsigned short (*Vt)[4096] = (unsigned short(*)[4096])(SM + 16384);
    unsigned short (*Pl)[4096] = (unsigned short(*)[4096])(SM + 32768);

    const unsigned short* QT = (const unsigned short*)(ws + O_QT);
    const unsigned short* KSP = (const unsigned short*)(ws + O_KSP);
    const unsigned short* VTg = (const unsigned short*)(ws + O_VT);
    unsigned short* NUM = (unsigned short*)(ws + O_NUM);
    float* DEN = (float*)(ws + O_DEN);

    const int b = blockIdx.x >> 6;
    const int qt = (blockIdx.x >> 4) & 3;
    const int s = blockIdx.x & 15;
    const int t = threadIdx.x;
    const int w = t >> 6, lane = t & 63;
    const int low4 = lane & 15, quad = lane >> 4;

    const unsigned short* KSPb = KSP + (size_t)b * 8192 * 64;
    const unsigned short* VTb = VTg + (size_t)b * 64 * 8192;
    const int qbase = qt * 256 + w * 64;
    const int kvbase = s * 512;

    int cn[2], cks[2], cqd[2], cl4[2];
#pragma unroll
    for (int pass = 0; pass < 2; ++pass) {
      const int c = pass * 256 + t;
      cn[pass] = c >> 7; cks[pass] = (c >> 6) & 1;
      cqd[pass] = (c >> 4) & 3; cl4[pass] = c & 15;
    }

    short8 qa[4][2];
#pragma unroll
    for (int mi = 0; mi < 4; ++mi)
#pragma unroll
      for (int ks = 0; ks < 2; ++ks)
        qa[mi][ks] = *(const short8*)(QT +
            ((size_t)(b * 1024 + qbase + mi * 16 + low4)) * 64 + ks * 32 + quad * 8);

    short8 vones;
#pragma unroll
    for (int j = 0; j < 8; ++j) vones[j] = (short)0x3F80;

    f4 accO[4][4], accD[4];
#pragma unroll
    for (int m = 0; m < 4; ++m) {
      accD[m] = (f4){0.f, 0.f, 0.f, 0.f};
#pragma unroll
      for (int n = 0; n < 4; ++n) accO[m][n] = (f4){0.f, 0.f, 0.f, 0.f};
    }

#pragma unroll
    for (int pass = 0; pass < 2; ++pass) {
      GLOAD_LDS16(KSPb + ((size_t)(kvbase + cn[pass] * 16 + cl4[pass])) * 64 +
                      cks[pass] * 32 + cqd[pass] * 8,
                  &Kt[0][(pass * 256 + w * 64) * 8]);
      GLOAD_LDS16(VTb + ((size_t)(cn[pass] * 16 + cl4[pass])) * 8192 + kvbase +
                      cks[pass] * 32 + cqd[pass] * 8,
                  &Vt[0][(pass * 256 + w * 64) * 8]);
    }

    const int pswz = ((low4 >> 2) & 3) << 1;
    for (int it = 0; it < 8; ++it) {
      const int d = it & 1;
      __syncthreads();
      if (it < 7) {
        const int kv1 = kvbase + (it + 1) * 64;
#pragma unroll
        for (int pass = 0; pass < 2; ++pass) {
          GLOAD_LDS16(KSPb + ((size_t)(kv1 + cn[pass] * 16 + cl4[pass])) * 64 +
                          cks[pass] * 32 + cqd[pass] * 8,
                      &Kt[d ^ 1][(pass * 256 + w * 64) * 8]);
          GLOAD_LDS16(VTb + ((size_t)(cn[pass] * 16 + cl4[pass])) * 8192 + kv1 +
                          cks[pass] * 32 + cqd[pass] * 8,
                      &Vt[d ^ 1][(pass * 256 + w * 64) * 8]);
        }
      }
#pragma unroll
      for (int n = 0; n < 4; ++n) {
        f4 sS[4];
#pragma unroll
        for (int mi = 0; mi < 4; ++mi) sS[mi] = (f4){0.f, 0.f, 0.f, 0.f};
#pragma unroll
        for (int ks = 0; ks < 2; ++ks) {
          short8 kb = *(const short8*)&Kt[d][((n * 2 + ks) * 64 + lane) * 8];
#pragma unroll
          for (int mi = 0; mi < 4; ++mi) sS[mi] = MFMA16(qa[mi][ks], kb, sS[mi]);
        }
        const int cpr = (((n * 2 + (low4 >> 3)) ^ (quad << 1)) << 3) + (low4 & 7);
#pragma unroll
        for (int mi = 0; mi < 4; ++mi) {
          unsigned short* pw = &Pl[w][(mi * 16 + quad * 4) * 64 + cpr];
#pragma unroll
          for (int r = 0; r < 4; ++r)
            pw[r * 64] = f2bf_rz(exp2fast(sS[mi][r]));
        }
      }
#pragma unroll
      for (int ks = 0; ks < 2; ++ks) {
        short8 vb[4];
#pragma unroll
        for (int n2 = 0; n2 < 4; ++n2)
          vb[n2] = *(const short8*)&Vt[d][((n2 * 2 + ks) * 64 + lane) * 8];
        const int cr = (((ks * 4 + quad) ^ pswz) << 3);
#pragma unroll
        for (int m = 0; m < 4; ++m) {
          short8 pa = *(const short8*)&Pl[w][(m * 16 + low4) * 64 + cr];
          accD[m] = MFMA16(pa, vones, accD[m]);
#pragma unroll
          for (int n2 = 0; n2 < 4; ++n2) accO[m][n2] = MFMA16(pa, vb[n2], accO[m][n2]);
        }
      }
    }

#pragma unroll
    for (int m = 0; m < 4; ++m)
#pragma unroll
      for (int r = 0; r < 4; ++r) {
        const int row = qbase + m * 16 + quad * 4 + r;
        const size_t base = ((size_t)(b * 1024 + row) * 16 + s);
#pragma unroll
        for (int n2 = 0; n2 < 4; ++n2)
          NUM[base * 64 + n2 * 16 + low4] = f2bf(accO[m][n2][r]);
        if (low4 == 0) DEN[base] = accD[m][r];
      }
    return;
  }

  // ================= chan_S =================
  {
    float* Sp = (float*)(ws + O_SP);
    const int bid = blockIdx.x - 512;
    const int b = bid >> 4, colT = (bid >> 2) & 3, kt = bid & 3;
    const int t = threadIdx.x, w = t >> 6, lane = t & 63;
    const int low4 = lane & 15, quad = lane >> 4;
    const int dl = lane >> 1, dh = lane & 1;
    const int k00 = kt * 256;

    // buf layout (per buf, 24576B): K f32 tile at +0 (16KB), Q at +16384 (8KB)
    f4 acc[4][2];
#pragma unroll
    for (int m = 0; m < 4; ++m)
#pragma unroll
      for (int n = 0; n < 2; ++n) acc[m][n] = (f4){0.f, 0.f, 0.f, 0.f};

    // stage one iter's tiles into buf at byte offset bo (6 DMA instrs/thread)
    auto stageAll = [&](int bo, int k0) {
#pragma unroll
      for (int gi = 0; gi < 4; ++gi) {           // K: groups w, w+4, w+8, w+12
        const int g = w + gi * 4;
        const int n = g >> 1, sub = g & 1;
        const int l = sub * 32 + dl;
        const float* gp = keys + (size_t)(b * 512 + colT * 128 + n * 16 + (l & 15)) * 1024
                          + k0 + (l >> 4) * 8 + dh * 4;
        GLOAD_LDS16(gp, SM + bo + (size_t)(n * 128 + sub * 64) * 16);
      }
#pragma unroll
      for (int gi = 0; gi < 2; ++gi) {           // Q: groups w, w+4
        const int g = w + gi * 4;
        const int m = g >> 1, sub = g & 1;
        const int l = sub * 32 + dl;
        const float* gp = q + (size_t)(b * 64 + m * 16 + (l & 15)) * 1024
                          + k0 + (l >> 4) * 8 + dh * 4;
        GLOAD_LDS16(gp, SM + bo + 16384 + (size_t)(m * 128 + sub * 64) * 16);
      }
    };

    stageAll(0, k00);
    for (int it = 0; it < 8; ++it) {
      const int bo = (it & 1) * 24576;
      const char* cb = (const char*)SM + bo;
      __syncthreads();
      if (it < 7) stageAll(bo ^ 24576, k00 + (it + 1) * 32);

      short8 ah[4], al[4];
#pragma unroll
      for (int m = 0; m < 4; ++m) {              // A-frags from LDS, *LOG2E, split
        const float* fp = (const float*)(cb + 16384 + (size_t)(m * 128 + lane * 2) * 16);
        float4 u0 = ((const float4*)fp)[0];
        float4 u1 = ((const float4*)fp)[1];
        float vv[8] = {u0.x, u0.y, u0.z, u0.w, u1.x, u1.y, u1.z, u1.w};
#pragma unroll
        for (int j = 0; j < 8; ++j) {
          float sv = vv[j] * LOG2E;
          unsigned short hi = f2bf(sv);
          ah[m][j] = (short)hi;
          al[m][j] = (short)f2bf(sv - bf2f(hi));
        }
      }
#pragma unroll
      for (int n2 = 0; n2 < 2; ++n2) {           // B-frags (this wave's 2 n-tiles)
        const int n = w * 2 + n2;
        const float* fp = (const float*)(cb + (size_t)(n * 128 + lane * 2) * 16);
        float4 u0 = ((const float4*)fp)[0];
        float4 u1 = ((const float4*)fp)[1];
        float vv[8] = {u0.x, u0.y, u0.z, u0.w, u1.x, u1.y, u1.z, u1.w};
        short8 bh, bl;
#pragma unroll
        for (int j = 0; j < 8; ++j) {
          unsigned short hi = f2bf(vv[j]);
          bh[j] = (short)hi;
          bl[j] = (short)f2bf(vv[j] - bf2f(hi));
        }
#pragma unroll
        for (int m = 0; m < 4; ++m) {
          acc[m][n2] = MFMA16(ah[m], bh, acc[m][n2]);
          acc[m][n2] = MFMA16(al[m], bh, acc[m][n2]);
          acc[m][n2] = MFMA16(ah[m], bl, acc[m][n2]);
        }
      }
    }

#pragma unroll
    for (int m = 0; m < 4; ++m)
#pragma unroll
      for (int n2 = 0; n2 < 2; ++n2)
#pragma unroll
        for (int r = 0; r < 4; ++r) {
          const int row = m * 16 + quad * 4 + r;
          const int col = colT * 128 + (w * 2 + n2) * 16 + low4;
          Sp[(((size_t)kt * 8 + b) * 64 + row) * 512 + col] = acc[m][n2][r];
        }
  }
}

// ============================================================================
// K3: spat_fin (blocks 0..511) ∪ chan_soft (512..543)
// ============================================================================
__global__ __launch_bounds__(256) void k3_fin_soft(char* __restrict__ ws)
{
  if (blockIdx.x < 512) {                // ---- spat_fin: 16 bf16 partials ----
    const unsigned short* NUM = (const unsigned short*)(ws + O_NUM);
    const float* DEN = (const float*)(ws + O_DEN);
    const unsigned short* QT = (const unsigned short*)(ws + O_QT);
    unsigned short* Xs = (unsigned short*)(ws + O_XS);

    const unsigned i = blockIdx.x * 256u + threadIdx.x;   // 131072
    const int c0 = (i & 15) * 4;
    const unsigned row = i >> 4;                          // [0, 8192)

    float dtot = 0.f;
#pragma unroll
    for (int sq = 0; sq < 4; ++sq) {
      float4 dv = *(const float4*)(DEN + (size_t)row * 16 + sq * 4);
      dtot += dv.x + dv.y + dv.z + dv.w;
    }
    float n4[4] = {0.f, 0.f, 0.f, 0.f};
#pragma unroll
    for (int s = 0; s < 16; ++s) {
      ushort4 pv = *(const ushort4*)(NUM + ((size_t)row * 16 + s) * 64 + c0);
      n4[0] += bf2f(pv.x); n4[1] += bf2f(pv.y);
      n4[2] += bf2f(pv.z); n4[3] += bf2f(pv.w);
    }
    const float rd = 1.0f / dtot;
    size_t ob = (size_t)row * 64 + c0;
    ushort4 qv = *(const ushort4*)(QT + ob);
    ushort4 o4;
    o4.x = f2bf(n4[0] * rd + bf2f(qv.x));
    o4.y = f2bf(n4[1] * rd + bf2f(qv.y));
    o4.z = f2bf(n4[2] * rd + bf2f(qv.z));
    o4.w = f2bf(n4[3] * rd + bf2f(qv.w));
    *(ushort4*)(Xs + ob) = o4;
    return;
  }

  // ---- chan_soft: sum 4 partials, max-sub, exp2, normalize -> P ----
  {
    const float* Sp = (const float*)(ws + O_SP);
    unsigned short* P = (unsigned short*)(ws + O_PCH);
    const int bid = blockIdx.x - 512;
    const int b = bid >> 2, rt = bid & 3;
    const int row = rt * 16 + (threadIdx.x >> 4), tc = threadIdx.x & 15;

    float sv[32];
    float mx = -1e30f;
#pragma unroll
    for (int jj = 0; jj < 32; ++jj) {
      const int col = jj * 16 + tc;
      size_t base = ((size_t)b * 64 + row) * 512 + col;
      float v = Sp[base] + Sp[base + 262144] + Sp[base + 524288] + Sp[base + 786432];
      sv[jj] = v;
      mx = fmaxf(mx, v);
    }
#pragma unroll
    for (int o = 1; o < 16; o <<= 1) mx = fmaxf(mx, __shfl_xor(mx, o, 64));
    float sum = 0.f;
#pragma unroll
    for (int jj = 0; jj < 32; ++jj) {
      float e = exp2fast(sv[jj] - mx);
      sv[jj] = e;
      sum += e;
    }
#pragma unroll
    for (int o = 1; o < 16; o <<= 1) sum += __shfl_xor(sum, o, 64);
    const float rs = 1.0f / sum;
#pragma unroll
    for (int jj = 0; jj < 32; ++jj)
      P[((size_t)b * 64 + row) * 512 + jj * 16 + tc] = f2bf(sv[jj] * rs);
  }
}

// ---------------- conv5 body (one stem): bid in [0,256) --------------------
__device__ __forceinline__ void conv5_body(char* ws, const float* b1p, int s, int bid)
{
  __shared__ float Hbuf[2][16][65];
  __shared__ float red[2][2];

  const int b = bid >> 5, pt = bid & 31;
  const int w = threadIdx.x >> 6, lane = threadIdx.x & 63;
  const int low4 = lane & 15, quad = lane >> 4;
  const int wsub = w & 1, half = w >> 1;

  const unsigned short* X = (const unsigned short*)(ws + (s ? O_XC : O_XS));
  const unsigned short* W1t = (const unsigned short*)(ws + O_W1T);
  unsigned short* Yt = (unsigned short*)(ws + O_YT);
  float* stats = (float*)(ws + O_STATS);

  const int p = pt * 32 + wsub * 16 + low4;
  const int y0 = p >> 5, x0 = p & 31;

  f4 acc[4];
#pragma unroll
  for (int m = 0; m < 4; ++m) acc[m] = (f4){0.f, 0.f, 0.f, 0.f};

  const int o0 = half ? 13 : 0, o1 = half ? 25 : 13;
  for (int off = o0; off < o1; ++off) {
    const int dy = off / 5 - 2, dx = off % 5 - 2;
    const int ys = y0 + dy, xs = x0 + dx;
    const bool valid = ((unsigned)ys < 32u) & ((unsigned)xs < 32u);
    const int psrc = valid ? (p + dy * 32 + dx) : p;
    const unsigned short* xp = X + ((size_t)(b * 1024 + psrc)) * 64;
    const unsigned short* wp = W1t + ((size_t)((s * 25 + off) * 64)) * 64;
#pragma unroll
    for (int ks = 0; ks < 2; ++ks) {
      short8 bv = *(const short8*)(xp + ks * 32 + quad * 8);
      if (!valid) bv = (short8)0;
#pragma unroll
      for (int m = 0; m < 4; ++m) {
        short8 av = *(const short8*)(wp + (m * 16 + low4) * 64 + ks * 32 + quad * 8);
        acc[m] = MFMA16(av, bv, acc[m]);
      }
    }
  }

  if (half) {
#pragma unroll
    for (int m = 0; m < 4; ++m)
#pragma unroll
      for (int r = 0; r < 4; ++r)
        Hbuf[wsub][low4][m * 16 + quad * 4 + r] = acc[m][r];
  }
  __syncthreads();
  if (!half) {
    float ls = 0.f, ls2 = 0.f;
#pragma unroll
    for (int m = 0; m < 4; ++m)
#pragma unroll
      for (int r = 0; r < 4; ++r) {
        const int co = m * 16 + quad * 4 + r;
        float y = acc[m][r] + Hbuf[wsub][low4][co] + b1p[co];
        Yt[((size_t)((s * 8 + b) * 1024 + p)) * 64 + co] = f2bf(y);
        ls += y; ls2 += y * y;
      }
#pragma unroll
    for (int o = 1; o < 64; o <<= 1) {
      ls += __shfl_xor(ls, o, 64);
      ls2 += __shfl_xor(ls2, o, 64);
    }
    if (lane == 0) { red[0][wsub] = ls; red[1][wsub] = ls2; }
  }
  __syncthreads();
  if (threadIdx.x == 0) {
    atomicAdd(&stats[(s * 8 + b) * 2 + 0], red[0][0] + red[0][1]);
    atomicAdd(&stats[(s * 8 + b) * 2 + 1], red[1][0] + red[1][1]);
  }
}

// ---------------- final body (one stem): bid in [0,256) --------------------
__device__ __forceinline__ void final_body(char* ws, const float* b2p,
                                           float* out, int s, int bid)
{
  const int b = bid >> 5, pt = bid & 31;
  const int w = threadIdx.x >> 6, lane = threadIdx.x & 63;
  const int low4 = lane & 15, quad = lane >> 4;
  const int p2 = pt * 32 + (w & 1) * 16 + low4;
  const int nh0 = (w >> 1) * 64;

  const unsigned short* Yt = (const unsigned short*)(ws + O_YT);
  const unsigned short* LNW = (const unsigned short*)(ws + O_LNW);
  const unsigned short* LNB = (const unsigned short*)(ws + O_LNB);
  const unsigned short* W2b = (const unsigned short*)(ws + O_W2B);
  const float* stats = (const float*)(ws + O_STATS);

  const float inv = 1.0f / 65536.0f;
  const float mu = stats[(s * 8 + b) * 2 + 0] * inv;
  const float ms = stats[(s * 8 + b) * 2 + 1] * inv;
  const float rsig = rsqrtf(ms - mu * mu + 1e-5f);

  f4 acc[4];
#pragma unroll
  for (int m = 0; m < 4; ++m) acc[m] = (f4){0.f, 0.f, 0.f, 0.f};

#pragma unroll
  for (int ks = 0; ks < 2; ++ks) {
    size_t yo = ((size_t)((s * 8 + b) * 1024 + p2)) * 64 + ks * 32 + quad * 8;
    size_t lo = ((size_t)(s * 1024 + p2)) * 64 + ks * 32 + quad * 8;
    short8 yv = *(const short8*)(Yt + yo);
    short8 lw8 = *(const short8*)(LNW + lo);
    short8 lb8 = *(const short8*)(LNB + lo);
    short8 zv;
#pragma unroll
    for (int j = 0; j < 8; ++j) {
      float z = (bf2f((unsigned short)yv[j]) - mu) * rsig * bf2f((unsigned short)lw8[j]) +
                bf2f((unsigned short)lb8[j]);
      zv[j] = (short)f2bf(fmaxf(z, 0.f));
    }
#pragma unroll
    for (int m = 0; m < 4; ++m) {
      short8 a = *(const short8*)(W2b + ((size_t)(s * 128 + nh0 + m * 16 + low4)) * 64 + ks * 32 + quad * 8);
      acc[m] = MFMA16(a, zv, acc[m]);
    }
  }
#pragma unroll
  for (int m = 0; m < 4; ++m)
#pragma unroll
    for (int r = 0; r < 4; ++r) {
      const int nh = nh0 + m * 16 + quad * 4 + r;
      out[((size_t)((s * 8 + b) * 128 + nh)) * 1024 + p2] = acc[m][r] + b2p[nh];
    }
}

// ============================================================================
// K4: conv5-spatial (0..255) ∪ chan_B (256..383)
// ============================================================================
__global__ __launch_bounds__(256) void k4_conv5s_chanB(
    const float* __restrict__ values, char* __restrict__ ws,
    const float* __restrict__ sb1)
{
  if (blockIdx.x < 256) { conv5_body(ws, sb1, 0, blockIdx.x); return; }

  // ---- chan_B: O = P @ V + residual (V gathered raw f32) ----
  const unsigned short* P = (const unsigned short*)(ws + O_PCH);
  const unsigned short* QT = (const unsigned short*)(ws + O_QT);
  unsigned short* Xc = (unsigned short*)(ws + O_XC);

  const int bid = blockIdx.x - 256;
  const int b = bid >> 4, pt = bid & 15;
  const int w = threadIdx.x >> 6, lane = threadIdx.x & 63;
  const int low4 = lane & 15, quad = lane >> 4;
  const int p = pt * 64 + w * 16 + low4;

  f4 acc[4];
#pragma unroll
  for (int m = 0; m < 4; ++m) acc[m] = (f4){0.f, 0.f, 0.f, 0.f};

  const float* vbase = values + (size_t)b * 524288 + p;
  for (int ks = 0; ks < 16; ++ks) {
    short8 vbv;
    const float* vp = vbase + (size_t)(ks * 32 + quad * 8) * 1024;
#pragma unroll
    for (int j = 0; j < 8; ++j) vbv[j] = (short)f2bf(vp[(size_t)j * 1024]);
#pragma unroll
    for (int m = 0; m < 4; ++m) {
      short8 a = *(const short8*)(P + ((size_t)(b * 64 + m * 16 + low4)) * 512 + ks * 32 + quad * 8);
      acc[m] = MFMA16(a, vbv, acc[m]);
    }
  }
#pragma unroll
  for (int m = 0; m < 4; ++m)
#pragma unroll
    for (int r = 0; r < 4; ++r) {
      const int c = m * 16 + quad * 4 + r;
      size_t o = ((size_t)(b * 1024 + p)) * 64 + c;
      Xc[o] = f2bf(acc[m][r] + bf2f(QT[o]));
    }
}

// ============================================================================
// K5: conv5-channel (0..255) ∪ final-spatial (256..511)
// ============================================================================
__global__ __launch_bounds__(256) void k5_conv5c_finS(
    char* __restrict__ ws, const float* __restrict__ cb1,
    const float* __restrict__ sb2, float* __restrict__ out)
{
  if (blockIdx.x < 256) { conv5_body(ws, cb1, 1, blockIdx.x); return; }
  final_body(ws, sb2, out, 0, blockIdx.x - 256);
}

// ============================================================================
// K6: final-channel (256 blocks)
// ============================================================================
__global__ __launch_bounds__(256) void k6_finC(
    char* __restrict__ ws, const float* __restrict__ cb2,
    float* __restrict__ out)
{
  final_body(ws, cb2, out, 1, blockIdx.x);
}

extern "C" void kernel_launch(void* const* d_in, const int* in_sizes, int n_in,
                              void* d_out, int out_size, void* d_ws, size_t ws_size,
                              hipStream_t stream)
{
  const float* q    = (const float*)d_in[0];
  const float* keys = (const float*)d_in[1];
  const float* vals = (const float*)d_in[2];
  const float* sw1  = (const float*)d_in[3];
  const float* sb1  = (const float*)d_in[4];
  const float* slnw = (const float*)d_in[5];
  const float* slnb = (const float*)d_in[6];
  const float* sw2  = (const float*)d_in[7];
  const float* sb2  = (const float*)d_in[8];
  const float* cw1  = (const float*)d_in[9];
  const float* cb1  = (const float*)d_in[10];
  const float* clnw = (const float*)d_in[11];
  const float* clnb = (const float*)d_in[12];
  const float* cw2  = (const float*)d_in[13];
  const float* cb2  = (const float*)d_in[14];
  char* ws = (char*)d_ws;

  (void)hipMemsetAsync(ws + O_STATS, 0, 256, stream);
  k1_prep<<<3104, 256, 0, stream>>>(q, keys, vals, sw1, slnw, slnb, sw2,
                                    cw1, clnw, clnb, cw2, ws);
  k2_spat_chanS<<<640, 256, 0, stream>>>(q, keys, ws);
  k3_fin_soft<<<544, 256, 0, stream>>>(ws);
  k4_conv5s_chanB<<<384, 256, 0, stream>>>(vals, ws, sb1);
  k5_conv5c_finS<<<512, 256, 0, stream>>>(ws, cb1, sb2, (float*)d_out);
  k6_finC<<<256, 256, 0, stream>>>(ws, cb2, (float*)d_out);
}